// Round 1
// baseline (639.499 us; speedup 1.0000x reference)
//
#include <hip/hip_runtime.h>
#include <math.h>

#define NN 10000
#define HEADS 8
#define FDIM 256
#define NCLS 40
#define CH 512
#define LOG2E 1.4426950408889634f

// ---------------- GEMM: C[M,N] = alpha * A[M,K] @ B[K,N] + bias ----------------
__global__ __launch_bounds__(256) void gemm_kernel(
    const float* __restrict__ A, const float* __restrict__ B,
    float* __restrict__ C, const float* __restrict__ bias,
    int M, int Nn, int K, float alpha)
{
    __shared__ float As[16][68];   // [k][m], padded stride 68 (16B-aligned rows)
    __shared__ float Bs[16][64];   // [k][n]
    const int tid = threadIdx.x;
    const int tx = tid & 15, ty = tid >> 4;
    const int row0 = blockIdx.x * 64, col0 = blockIdx.y * 64;
    float acc[4][4] = {};
    for (int k0 = 0; k0 < K; k0 += 16) {
        #pragma unroll
        for (int i = 0; i < 4; i++) {
            int l = tid + i * 256;          // 0..1023 over 64x16 tile
            int r = l >> 4, c = l & 15;
            int gr = row0 + r;
            As[c][r] = (gr < M) ? A[(size_t)gr * K + k0 + c] : 0.f;
        }
        #pragma unroll
        for (int i = 0; i < 4; i++) {
            int l = tid + i * 256;          // over 16x64 tile
            int c = l >> 6, r = l & 63;
            int gc = col0 + r;
            Bs[c][r] = (gc < Nn) ? B[(size_t)(k0 + c) * Nn + gc] : 0.f;
        }
        __syncthreads();
        #pragma unroll
        for (int kk = 0; kk < 16; kk++) {
            float a[4], b[4];
            #pragma unroll
            for (int i = 0; i < 4; i++) a[i] = As[kk][ty * 4 + i];
            #pragma unroll
            for (int j = 0; j < 4; j++) b[j] = Bs[kk][tx * 4 + j];
            #pragma unroll
            for (int i = 0; i < 4; i++)
                #pragma unroll
                for (int j = 0; j < 4; j++)
                    acc[i][j] += a[i] * b[j];
        }
        __syncthreads();
    }
    #pragma unroll
    for (int i = 0; i < 4; i++) {
        int gr = row0 + ty * 4 + i;
        if (gr >= M) continue;
        #pragma unroll
        for (int j = 0; j < 4; j++) {
            int gc = col0 + tx * 4 + j;
            if (gc < Nn) {
                float v = acc[i][j] * alpha;
                if (bias) v += bias[gc];
                C[(size_t)gr * Nn + gc] = v;
            }
        }
    }
}

// ---------------- CSR build ----------------
__global__ void init_counts_kernel(int* counts, int n) {
    int i = blockIdx.x * 256 + threadIdx.x;
    if (i < n) counts[i] = 1;   // self loop
}

__global__ void count_edges_kernel(const int* __restrict__ dst, int* counts, int E) {
    int e = blockIdx.x * 256 + threadIdx.x;
    if (e < E) atomicAdd(&counts[dst[e]], 1);
}

__global__ __launch_bounds__(1024) void scan_kernel(
    const int* __restrict__ counts, int* offsets, int* cursor, int* elist, int n)
{
    __shared__ int temp[1024];
    __shared__ int carry_s;
    if (threadIdx.x == 0) carry_s = 0;
    __syncthreads();
    for (int base = 0; base < n; base += 1024) {
        int i = base + threadIdx.x;
        int v = (i < n) ? counts[i] : 0;
        temp[threadIdx.x] = v;
        __syncthreads();
        for (int off = 1; off < 1024; off <<= 1) {
            int t = (threadIdx.x >= off) ? temp[threadIdx.x - off] : 0;
            __syncthreads();
            temp[threadIdx.x] += t;
            __syncthreads();
        }
        int carry = carry_s;
        int excl = temp[threadIdx.x] - v + carry;
        if (i < n) {
            offsets[i] = excl;
            elist[excl] = i;        // self-loop occupies first slot
            cursor[i] = excl + 1;
        }
        __syncthreads();
        if (threadIdx.x == 1023) carry_s = carry + temp[1023];
        __syncthreads();
    }
}

__global__ void scatter_edges_kernel(const int* __restrict__ src, const int* __restrict__ dst,
                                     int* cursor, int* elist, int E) {
    int e = blockIdx.x * 256 + threadIdx.x;
    if (e < E) {
        int d = dst[e];
        int pos = atomicAdd(&cursor[d], 1);
        elist[pos] = src[e];
    }
}

// ---------------- attention scores ----------------
// layer 0: s0[n,0..7]=src score, s0[n,8..15]=dst score, from h0 [N,256] with a[8,32]
__global__ __launch_bounds__(256) void score0_kernel(
    const float* __restrict__ h0, const float* __restrict__ a_src,
    const float* __restrict__ a_dst, float* __restrict__ s0)
{
    int n = blockIdx.x, t = threadIdx.x;
    float v = h0[n * 256 + t];
    float ps = v * a_src[t];
    float pd = v * a_dst[t];
    #pragma unroll
    for (int off = 16; off >= 1; off >>= 1) {
        ps += __shfl_down(ps, off, 32);
        pd += __shfl_down(pd, off, 32);
    }
    if ((t & 31) == 0) {
        int h = t >> 5;
        s0[n * 16 + h] = ps;
        s0[n * 16 + 8 + h] = pd;
    }
}

// v1[f*16+j]: j<8 -> src head j; j>=8 -> dst head j-8   (folded W1·a)
__global__ void prep_v1_kernel(const float* __restrict__ W1, const float* __restrict__ a_src1,
                               const float* __restrict__ a_dst1, float* __restrict__ v1)
{
    int idx = blockIdx.x * 256 + threadIdx.x;
    if (idx >= 256 * 16) return;
    int f = idx >> 4, j = idx & 15;
    int h = j & 7;
    const float* a = (j < 8) ? a_src1 : a_dst1;
    float s = 0.f;
    for (int c = 0; c < 256; c++)
        s += W1[f * 2048 + h * 256 + c] * a[h * 256 + c];
    v1[idx] = s;
}

// s1[n,0..15] = h_act0[n,:] @ v1[:,16]
__global__ __launch_bounds__(256) void score1_kernel(
    const float* __restrict__ h, const float* __restrict__ v1, float* __restrict__ s1)
{
    __shared__ float row[256];
    __shared__ float part[16][17];
    int n = blockIdx.x, t = threadIdx.x;
    row[t] = h[n * 256 + t];
    __syncthreads();
    int j = t & 15, f0 = t >> 4;
    float p = 0.f;
    #pragma unroll
    for (int k = 0; k < 16; k++) {
        int f = f0 * 16 + k;
        p += row[f] * v1[f * 16 + j];
    }
    part[f0][j] = p;
    __syncthreads();
    if (t < 16) {
        float s = 0.f;
        #pragma unroll
        for (int k = 0; k < 16; k++) s += part[k][t];
        s1[n * 16 + t] = s;
    }
}

// ---------------- layer-0 aggregation (output space, C=32/head) ----------------
__global__ __launch_bounds__(256) void agg0_kernel(
    const float* __restrict__ h0, const float* __restrict__ s0,
    const int* __restrict__ offsets, const int* __restrict__ counts,
    const int* __restrict__ elist, const float* __restrict__ b0,
    float* __restrict__ out)
{
    __shared__ float p[CH * 8];
    __shared__ int sl[CH];
    __shared__ float sred[4][8];
    __shared__ float rm[8], rl[8], sscale[8], sd[8];
    int n = blockIdx.x, t = threadIdx.x;
    int deg = counts[n], start = offsets[n];
    if (t < 8) { rm[t] = -INFINITY; rl[t] = 0.f; sd[t] = s0[n * 16 + 8 + t]; }
    __syncthreads();
    float acc = 0.f;
    int myh = t >> 5;
    for (int e0 = 0; e0 < deg; e0 += CH) {
        int ch = min(CH, deg - e0);
        int items = ch * 8;
        for (int idx = t; idx < items; idx += 256) {
            int e = idx >> 3, h = idx & 7;
            int sn = elist[start + e0 + e];
            if (h == 0) sl[e] = sn;
            float sc = s0[sn * 16 + h] + sd[h];
            sc = (sc > 0.f) ? sc : 0.2f * sc;
            p[idx] = sc;
        }
        __syncthreads();
        {   // per-head chunk max
            int h = t & 7;
            float mloc = -INFINITY;
            for (int e = t >> 3; e < ch; e += 32) mloc = fmaxf(mloc, p[e * 8 + h]);
            #pragma unroll
            for (int off = 8; off <= 32; off <<= 1) mloc = fmaxf(mloc, __shfl_xor(mloc, off, 64));
            if ((t & 63) < 8) sred[t >> 6][t & 7] = mloc;
        }
        __syncthreads();
        if (t < 8) {
            float cm = fmaxf(fmaxf(sred[0][t], sred[1][t]), fmaxf(sred[2][t], sred[3][t]));
            float mnew = fmaxf(rm[t], cm);
            float sc_ = exp2f((rm[t] - mnew) * LOG2E);
            sscale[t] = sc_;
            rm[t] = mnew;
            rl[t] *= sc_;
        }
        __syncthreads();
        acc *= sscale[myh];
        for (int idx = t; idx < items; idx += 256) {
            int h = idx & 7;
            p[idx] = exp2f((p[idx] - rm[h]) * LOG2E);
        }
        __syncthreads();
        {   // per-head chunk sum
            int h = t & 7;
            float sloc = 0.f;
            for (int e = t >> 3; e < ch; e += 32) sloc += p[e * 8 + h];
            #pragma unroll
            for (int off = 8; off <= 32; off <<= 1) sloc += __shfl_xor(sloc, off, 64);
            if ((t & 63) < 8) sred[t >> 6][t & 7] = sloc;
        }
        __syncthreads();
        if (t < 8) rl[t] += sred[0][t] + sred[1][t] + sred[2][t] + sred[3][t];
        // phase 2: weighted accumulate
        for (int e = 0; e < ch; e++) {
            int sn = sl[e];
            acc += p[e * 8 + myh] * h0[sn * 256 + t];
        }
        __syncthreads();
    }
    out[n * 256 + t] = acc / rl[myh] + b0[t];
}

// ---------------- layer-1 aggregation (input space: agg[n,h,f]) ----------------
__global__ __launch_bounds__(256) void agg1_kernel(
    const float* __restrict__ hact, const float* __restrict__ s1,
    const int* __restrict__ offsets, const int* __restrict__ counts,
    const int* __restrict__ elist, float* __restrict__ aggout)
{
    __shared__ float p[CH * 8];
    __shared__ int sl[CH];
    __shared__ float sred[4][8];
    __shared__ float rm[8], rl[8], sscale[8], sd[8];
    int n = blockIdx.x, t = threadIdx.x;
    int deg = counts[n], start = offsets[n];
    if (t < 8) { rm[t] = -INFINITY; rl[t] = 0.f; sd[t] = s1[n * 16 + 8 + t]; }
    __syncthreads();
    float acc[8] = {};
    for (int e0 = 0; e0 < deg; e0 += CH) {
        int ch = min(CH, deg - e0);
        int items = ch * 8;
        for (int idx = t; idx < items; idx += 256) {
            int e = idx >> 3, h = idx & 7;
            int sn = elist[start + e0 + e];
            if (h == 0) sl[e] = sn;
            float sc = s1[sn * 16 + h] + sd[h];
            sc = (sc > 0.f) ? sc : 0.2f * sc;
            p[idx] = sc;
        }
        __syncthreads();
        {
            int h = t & 7;
            float mloc = -INFINITY;
            for (int e = t >> 3; e < ch; e += 32) mloc = fmaxf(mloc, p[e * 8 + h]);
            #pragma unroll
            for (int off = 8; off <= 32; off <<= 1) mloc = fmaxf(mloc, __shfl_xor(mloc, off, 64));
            if ((t & 63) < 8) sred[t >> 6][t & 7] = mloc;
        }
        __syncthreads();
        if (t < 8) {
            float cm = fmaxf(fmaxf(sred[0][t], sred[1][t]), fmaxf(sred[2][t], sred[3][t]));
            float mnew = fmaxf(rm[t], cm);
            float sc_ = exp2f((rm[t] - mnew) * LOG2E);
            sscale[t] = sc_;
            rm[t] = mnew;
            rl[t] *= sc_;
        }
        __syncthreads();
        #pragma unroll
        for (int h = 0; h < 8; h++) acc[h] *= sscale[h];
        for (int idx = t; idx < items; idx += 256) {
            int h = idx & 7;
            p[idx] = exp2f((p[idx] - rm[h]) * LOG2E);
        }
        __syncthreads();
        {
            int h = t & 7;
            float sloc = 0.f;
            for (int e = t >> 3; e < ch; e += 32) sloc += p[e * 8 + h];
            #pragma unroll
            for (int off = 8; off <= 32; off <<= 1) sloc += __shfl_xor(sloc, off, 64);
            if ((t & 63) < 8) sred[t >> 6][t & 7] = sloc;
        }
        __syncthreads();
        if (t < 8) rl[t] += sred[0][t] + sred[1][t] + sred[2][t] + sred[3][t];
        for (int e = 0; e < ch; e++) {
            int sn = sl[e];
            float v = hact[sn * 256 + t];
            #pragma unroll
            for (int h = 0; h < 8; h++) acc[h] += p[e * 8 + h] * v;
        }
        __syncthreads();
    }
    #pragma unroll
    for (int h = 0; h < 8; h++)
        aggout[(size_t)n * 2048 + h * 256 + t] = acc[h] / rl[h];
}

// W1p[(h*256+f)*256 + c] = W1[f*2048 + h*256 + c]
__global__ void perm_w1_kernel(const float* __restrict__ W1, float* __restrict__ W1p) {
    int k = blockIdx.x;       // 0..2047 : h*256+f
    int c = threadIdx.x;      // 0..255
    int h = k >> 8, f = k & 255;
    W1p[(size_t)k * 256 + c] = W1[(size_t)f * 2048 + h * 256 + c];
}

// ---------------- batchnorm ----------------
__global__ __launch_bounds__(256) void bn_stats_kernel(const float* __restrict__ x, float* stats, int n) {
    int t = threadIdx.x;
    float s = 0.f, s2 = 0.f;
    for (int r = blockIdx.x; r < n; r += gridDim.x) {
        float v = x[(size_t)r * 256 + t];
        s += v; s2 += v * v;
    }
    atomicAdd(&stats[t], s);
    atomicAdd(&stats[256 + t], s2);
}

__global__ __launch_bounds__(256) void bn_apply_kernel(
    const float* __restrict__ x, const float* __restrict__ stats,
    const float* __restrict__ g, const float* __restrict__ be,
    const float* __restrict__ resid, float* __restrict__ y, int total)
{
    int i = blockIdx.x * 256 + threadIdx.x;
    if (i >= total) return;
    int c = i & 255;
    const float invN = 1.0f / NN;
    float mu = stats[c] * invN;
    float var = stats[256 + c] * invN - mu * mu;
    float v = g[c] * (x[i] - mu) * rsqrtf(var + 1e-5f) + be[c];
    v = (v > 0.f) ? v : (expf(v) - 1.f);   // ELU
    if (resid) v += resid[i];
    y[i] = v;
}

// ---------------- launch ----------------
extern "C" void kernel_launch(void* const* d_in, const int* in_sizes, int n_in,
                              void* d_out, int out_size, void* d_ws, size_t ws_size,
                              hipStream_t stream) {
    const float* x      = (const float*)d_in[0];
    const int*   eidx   = (const int*)d_in[1];
    const float* W0     = (const float*)d_in[2];
    const float* a_src0 = (const float*)d_in[3];
    const float* a_dst0 = (const float*)d_in[4];
    const float* b0     = (const float*)d_in[5];
    const float* g0     = (const float*)d_in[6];
    const float* be0    = (const float*)d_in[7];
    const float* W1     = (const float*)d_in[8];
    const float* a_src1 = (const float*)d_in[9];
    const float* a_dst1 = (const float*)d_in[10];
    const float* b1     = (const float*)d_in[11];
    const float* g1     = (const float*)d_in[12];
    const float* be1    = (const float*)d_in[13];
    const float* Wc     = (const float*)d_in[14];
    const float* bc     = (const float*)d_in[15];
    float* out = (float*)d_out;

    const int E = in_sizes[1] / 2;
    const int* esrc = eidx;
    const int* edst = eidx + E;

    // workspace carve-up (256B aligned)
    char* ws = (char*)d_ws;
    size_t off = 0;
    auto alloc = [&](size_t bytes) {
        void* p = ws + off;
        off += (bytes + 255) & ~(size_t)255;
        return p;
    };
    float* buf0   = (float*)alloc((size_t)NN * 256 * 4);   // h0, later out1
    float* s0     = (float*)alloc((size_t)NN * 16 * 4);
    float* s1     = (float*)alloc((size_t)NN * 16 * 4);
    float* v1     = (float*)alloc(4096 * 4);
    float* buf4   = (float*)alloc((size_t)NN * 256 * 4);   // h_gat0, later h_final
    float* hact   = (float*)alloc((size_t)NN * 256 * 4);
    float* agg1   = (float*)alloc((size_t)NN * 2048 * 4);
    float* W1p    = (float*)alloc((size_t)2048 * 256 * 4);
    float* stats  = (float*)alloc(1024 * 4);               // [0:512) layer0, [512:1024) layer1
    int* counts   = (int*)alloc(NN * 4);
    int* offsets  = (int*)alloc((NN + 16) * 4);
    int* cursor   = (int*)alloc(NN * 4);
    int* elist    = (int*)alloc((size_t)(E + NN) * 4);

    float* h0      = buf0;
    float* out1    = buf0;
    float* h_gat0  = buf4;
    float* h_final = buf4;
    float* stats0  = stats;
    float* stats1  = stats + 512;

    hipMemsetAsync(stats, 0, 1024 * 4, stream);

    // CSR build
    init_counts_kernel<<<(NN + 255) / 256, 256, 0, stream>>>(counts, NN);
    count_edges_kernel<<<(E + 255) / 256, 256, 0, stream>>>(edst, counts, E);
    scan_kernel<<<1, 1024, 0, stream>>>(counts, offsets, cursor, elist, NN);
    scatter_edges_kernel<<<(E + 255) / 256, 256, 0, stream>>>(esrc, edst, cursor, elist, E);

    // small precomputes
    prep_v1_kernel<<<16, 256, 0, stream>>>(W1, a_src1, a_dst1, v1);
    perm_w1_kernel<<<2048, 256, 0, stream>>>(W1, W1p);

    // layer 0
    {
        dim3 grid((NN + 63) / 64, (256 + 63) / 64);
        gemm_kernel<<<grid, 256, 0, stream>>>(x, W0, h0, nullptr, NN, 256, 256, 1.0f);
    }
    score0_kernel<<<NN, 256, 0, stream>>>(h0, a_src0, a_dst0, s0);
    agg0_kernel<<<NN, 256, 0, stream>>>(h0, s0, offsets, counts, elist, b0, h_gat0);
    bn_stats_kernel<<<128, 256, 0, stream>>>(h_gat0, stats0, NN);
    bn_apply_kernel<<<(NN * 256 + 255) / 256, 256, 0, stream>>>(
        h_gat0, stats0, g0, be0, nullptr, hact, NN * 256);

    // layer 1
    score1_kernel<<<NN, 256, 0, stream>>>(hact, v1, s1);
    agg1_kernel<<<NN, 256, 0, stream>>>(hact, s1, offsets, counts, elist, agg1);
    {
        dim3 grid((NN + 63) / 64, (256 + 63) / 64);
        gemm_kernel<<<grid, 256, 0, stream>>>(agg1, W1p, out1, b1, NN, 256, 2048, 0.125f);
    }
    bn_stats_kernel<<<128, 256, 0, stream>>>(out1, stats1, NN);
    bn_apply_kernel<<<(NN * 256 + 255) / 256, 256, 0, stream>>>(
        out1, stats1, g1, be1, hact, h_final, NN * 256);

    // classifier
    {
        dim3 grid((NN + 63) / 64, 1);
        gemm_kernel<<<grid, 256, 0, stream>>>(h_final, Wc, out, bc, NN, NCLS, 256, 1.0f);
    }
}

// Round 2
// 411.889 us; speedup vs baseline: 1.5526x; 1.5526x over previous
//
#include <hip/hip_runtime.h>
#include <math.h>

#define NN 10000
#define HEADS 8
#define FDIM 256
#define NCLS 40
#define CH 512
#define LOG2E 1.4426950408889634f

typedef __attribute__((ext_vector_type(8))) short short8;
typedef __attribute__((ext_vector_type(4))) float floatx4;

static __device__ __forceinline__ short f2bf(float f) {
    unsigned u = __builtin_bit_cast(unsigned, f);
    unsigned r = (u + 0x7fff + ((u >> 16) & 1)) >> 16;
    return (short)r;
}

// ---------------- fp32 GEMM (layer 0 only): C = alpha*A@B + bias ----------------
__global__ __launch_bounds__(256) void gemm_kernel(
    const float* __restrict__ A, const float* __restrict__ B,
    float* __restrict__ C, const float* __restrict__ bias,
    int M, int Nn, int K, float alpha)
{
    __shared__ float As[16][68];
    __shared__ float Bs[16][64];
    const int tid = threadIdx.x;
    const int tx = tid & 15, ty = tid >> 4;
    const int row0 = blockIdx.x * 64, col0 = blockIdx.y * 64;
    float acc[4][4] = {};
    for (int k0 = 0; k0 < K; k0 += 16) {
        #pragma unroll
        for (int i = 0; i < 4; i++) {
            int l = tid + i * 256;
            int r = l >> 4, c = l & 15;
            int gr = row0 + r;
            As[c][r] = (gr < M) ? A[(size_t)gr * K + k0 + c] : 0.f;
        }
        #pragma unroll
        for (int i = 0; i < 4; i++) {
            int l = tid + i * 256;
            int c = l >> 6, r = l & 63;
            int gc = col0 + r;
            Bs[c][r] = (gc < Nn) ? B[(size_t)(k0 + c) * Nn + gc] : 0.f;
        }
        __syncthreads();
        #pragma unroll
        for (int kk = 0; kk < 16; kk++) {
            float a[4], b[4];
            #pragma unroll
            for (int i = 0; i < 4; i++) a[i] = As[kk][ty * 4 + i];
            #pragma unroll
            for (int j = 0; j < 4; j++) b[j] = Bs[kk][tx * 4 + j];
            #pragma unroll
            for (int i = 0; i < 4; i++)
                #pragma unroll
                for (int j = 0; j < 4; j++)
                    acc[i][j] += a[i] * b[j];
        }
        __syncthreads();
    }
    #pragma unroll
    for (int i = 0; i < 4; i++) {
        int gr = row0 + ty * 4 + i;
        if (gr >= M) continue;
        #pragma unroll
        for (int j = 0; j < 4; j++) {
            int gc = col0 + tx * 4 + j;
            if (gc < Nn) {
                float v = acc[i][j] * alpha;
                if (bias) v += bias[gc];
                C[(size_t)gr * Nn + gc] = v;
            }
        }
    }
}

// ---------------- bf16 MFMA GEMM: C[M,N] = alpha * A[M,K] @ Bt[N,K]^T + bias ----------------
// BM=128, BN=64, BK=32; 256 threads = 4 waves; wave w: rows [w*32, w*32+32), all 64 cols.
__global__ __launch_bounds__(256) void gemm_bf16_kernel(
    const short* __restrict__ A, const short* __restrict__ Bt,
    float* __restrict__ C, const float* __restrict__ bias,
    int M, int Nn, int K, float alpha)
{
    __shared__ short As[128 * 40];   // [row][k], stride 40 (20 banks -> conflict-free-ish)
    __shared__ short Bs[64 * 40];    // [n][k]
    const int tid = threadIdx.x;
    const int w = tid >> 6, L = tid & 63;
    const int quad = L >> 4, lr = L & 15;
    const int row0 = blockIdx.x * 128, col0 = blockIdx.y * 64;

    floatx4 acc[2][4];
    const floatx4 zf = {0.f, 0.f, 0.f, 0.f};
    #pragma unroll
    for (int i = 0; i < 2; i++)
        #pragma unroll
        for (int j = 0; j < 4; j++) acc[i][j] = zf;
    const short8 zs = {0, 0, 0, 0, 0, 0, 0, 0};

    for (int k0 = 0; k0 < K; k0 += 32) {
        // stage A: 128x32 bf16 = 512 chunks of 8
        #pragma unroll
        for (int it = 0; it < 2; it++) {
            int q = tid + it * 256;
            int r = q >> 2, kq = (q & 3) * 8;
            int gr = row0 + r;
            short8 v = (gr < M) ? *(const short8*)(A + (size_t)gr * K + k0 + kq) : zs;
            *(short8*)&As[r * 40 + kq] = v;
        }
        // stage B: 64x32 bf16 = 256 chunks
        {
            int r = tid >> 2, kq = (tid & 3) * 8;
            int gc = col0 + r;
            short8 v = (gc < Nn) ? *(const short8*)(Bt + (size_t)gc * K + k0 + kq) : zs;
            *(short8*)&Bs[r * 40 + kq] = v;
        }
        __syncthreads();
        short8 af[2], bf[4];
        #pragma unroll
        for (int i = 0; i < 2; i++)
            af[i] = *(const short8*)&As[(w * 32 + i * 16 + lr) * 40 + quad * 8];
        #pragma unroll
        for (int j = 0; j < 4; j++)
            bf[j] = *(const short8*)&Bs[(j * 16 + lr) * 40 + quad * 8];
        #pragma unroll
        for (int i = 0; i < 2; i++)
            #pragma unroll
            for (int j = 0; j < 4; j++)
                acc[i][j] = __builtin_amdgcn_mfma_f32_16x16x32_bf16(af[i], bf[j], acc[i][j], 0, 0, 0);
        __syncthreads();
    }
    // store: C/D layout col=lane&15, row=quad*4+reg
    #pragma unroll
    for (int i = 0; i < 2; i++) {
        #pragma unroll
        for (int j = 0; j < 4; j++) {
            int col = col0 + j * 16 + lr;
            if (col >= Nn) continue;
            float bv = bias ? bias[col] : 0.f;
            #pragma unroll
            for (int r = 0; r < 4; r++) {
                int row = row0 + w * 32 + i * 16 + quad * 4 + r;
                if (row < M) C[(size_t)row * Nn + col] = alpha * acc[i][j][r] + bv;
            }
        }
    }
}

// ---------------- CSR build ----------------
__global__ void init_counts_kernel(int* counts, int n) {
    int i = blockIdx.x * 256 + threadIdx.x;
    if (i < n) counts[i] = 1;
}

__global__ void count_edges_kernel(const int* __restrict__ dst, int* counts, int E) {
    int e = blockIdx.x * 256 + threadIdx.x;
    if (e < E) atomicAdd(&counts[dst[e]], 1);
}

__global__ __launch_bounds__(1024) void scan_kernel(
    const int* __restrict__ counts, int* offsets, int* cursor, int* elist, int n)
{
    __shared__ int temp[1024];
    __shared__ int carry_s;
    if (threadIdx.x == 0) carry_s = 0;
    __syncthreads();
    for (int base = 0; base < n; base += 1024) {
        int i = base + threadIdx.x;
        int v = (i < n) ? counts[i] : 0;
        temp[threadIdx.x] = v;
        __syncthreads();
        for (int off = 1; off < 1024; off <<= 1) {
            int t = (threadIdx.x >= off) ? temp[threadIdx.x - off] : 0;
            __syncthreads();
            temp[threadIdx.x] += t;
            __syncthreads();
        }
        int carry = carry_s;
        int excl = temp[threadIdx.x] - v + carry;
        if (i < n) {
            offsets[i] = excl;
            elist[excl] = i;
            cursor[i] = excl + 1;
        }
        __syncthreads();
        if (threadIdx.x == 1023) carry_s = carry + temp[1023];
        __syncthreads();
    }
}

__global__ void scatter_edges_kernel(const int* __restrict__ src, const int* __restrict__ dst,
                                     int* cursor, int* elist, int E) {
    int e = blockIdx.x * 256 + threadIdx.x;
    if (e < E) {
        int d = dst[e];
        int pos = atomicAdd(&cursor[d], 1);
        elist[pos] = src[e];
    }
}

// ---------------- attention scores ----------------
__global__ __launch_bounds__(256) void score0_kernel(
    const float* __restrict__ h0, const float* __restrict__ a_src,
    const float* __restrict__ a_dst, float* __restrict__ s0)
{
    int n = blockIdx.x, t = threadIdx.x;
    float v = h0[n * 256 + t];
    float ps = v * a_src[t];
    float pd = v * a_dst[t];
    #pragma unroll
    for (int off = 16; off >= 1; off >>= 1) {
        ps += __shfl_down(ps, off, 32);
        pd += __shfl_down(pd, off, 32);
    }
    if ((t & 31) == 0) {
        int h = t >> 5;
        s0[n * 16 + h] = ps;
        s0[n * 16 + 8 + h] = pd;
    }
}

__global__ void prep_v1_kernel(const float* __restrict__ W1, const float* __restrict__ a_src1,
                               const float* __restrict__ a_dst1, float* __restrict__ v1)
{
    int idx = blockIdx.x * 256 + threadIdx.x;
    if (idx >= 256 * 16) return;
    int f = idx >> 4, j = idx & 15;
    int h = j & 7;
    const float* a = (j < 8) ? a_src1 : a_dst1;
    float s = 0.f;
    for (int c = 0; c < 256; c++)
        s += W1[f * 2048 + h * 256 + c] * a[h * 256 + c];
    v1[idx] = s;
}

__global__ __launch_bounds__(256) void score1_kernel(
    const float* __restrict__ h, const float* __restrict__ v1, float* __restrict__ s1)
{
    __shared__ float row[256];
    __shared__ float part[16][17];
    int n = blockIdx.x, t = threadIdx.x;
    row[t] = h[n * 256 + t];
    __syncthreads();
    int j = t & 15, f0 = t >> 4;
    float p = 0.f;
    #pragma unroll
    for (int k = 0; k < 16; k++) {
        int f = f0 * 16 + k;
        p += row[f] * v1[f * 16 + j];
    }
    part[f0][j] = p;
    __syncthreads();
    if (t < 16) {
        float s = 0.f;
        #pragma unroll
        for (int k = 0; k < 16; k++) s += part[k][t];
        s1[n * 16 + t] = s;
    }
}

// ---------------- layer-0 aggregation ----------------
__global__ __launch_bounds__(256) void agg0_kernel(
    const float* __restrict__ h0, const float* __restrict__ s0,
    const int* __restrict__ offsets, const int* __restrict__ counts,
    const int* __restrict__ elist, const float* __restrict__ b0,
    float* __restrict__ out)
{
    __shared__ float p[CH * 8];
    __shared__ int sl[CH];
    __shared__ float sred[4][8];
    __shared__ float rm[8], rl[8], sscale[8], sd[8];
    int n = blockIdx.x, t = threadIdx.x;
    int deg = counts[n], start = offsets[n];
    if (t < 8) { rm[t] = -INFINITY; rl[t] = 0.f; sd[t] = s0[n * 16 + 8 + t]; }
    __syncthreads();
    float acc = 0.f;
    int myh = t >> 5;
    for (int e0 = 0; e0 < deg; e0 += CH) {
        int ch = min(CH, deg - e0);
        int items = ch * 8;
        for (int idx = t; idx < items; idx += 256) {
            int e = idx >> 3, h = idx & 7;
            int sn = elist[start + e0 + e];
            if (h == 0) sl[e] = sn;
            float sc = s0[sn * 16 + h] + sd[h];
            sc = (sc > 0.f) ? sc : 0.2f * sc;
            p[idx] = sc;
        }
        __syncthreads();
        {
            int h = t & 7;
            float mloc = -INFINITY;
            for (int e = t >> 3; e < ch; e += 32) mloc = fmaxf(mloc, p[e * 8 + h]);
            #pragma unroll
            for (int off = 8; off <= 32; off <<= 1) mloc = fmaxf(mloc, __shfl_xor(mloc, off, 64));
            if ((t & 63) < 8) sred[t >> 6][t & 7] = mloc;
        }
        __syncthreads();
        if (t < 8) {
            float cm = fmaxf(fmaxf(sred[0][t], sred[1][t]), fmaxf(sred[2][t], sred[3][t]));
            float mnew = fmaxf(rm[t], cm);
            float sc_ = exp2f((rm[t] - mnew) * LOG2E);
            sscale[t] = sc_;
            rm[t] = mnew;
            rl[t] *= sc_;
        }
        __syncthreads();
        acc *= sscale[myh];
        for (int idx = t; idx < items; idx += 256) {
            int h = idx & 7;
            p[idx] = exp2f((p[idx] - rm[h]) * LOG2E);
        }
        __syncthreads();
        {
            int h = t & 7;
            float sloc = 0.f;
            for (int e = t >> 3; e < ch; e += 32) sloc += p[e * 8 + h];
            #pragma unroll
            for (int off = 8; off <= 32; off <<= 1) sloc += __shfl_xor(sloc, off, 64);
            if ((t & 63) < 8) sred[t >> 6][t & 7] = sloc;
        }
        __syncthreads();
        if (t < 8) rl[t] += sred[0][t] + sred[1][t] + sred[2][t] + sred[3][t];
        for (int e = 0; e < ch; e++) {
            int sn = sl[e];
            acc += p[e * 8 + myh] * h0[sn * 256 + t];
        }
        __syncthreads();
    }
    out[n * 256 + t] = acc / rl[myh] + b0[t];
}

// ---------------- layer-1 aggregation (writes bf16) ----------------
__global__ __launch_bounds__(256) void agg1_kernel(
    const float* __restrict__ hact, const float* __restrict__ s1,
    const int* __restrict__ offsets, const int* __restrict__ counts,
    const int* __restrict__ elist, short* __restrict__ aggout)
{
    __shared__ float p[CH * 8];
    __shared__ int sl[CH];
    __shared__ float sred[4][8];
    __shared__ float rm[8], rl[8], sscale[8], sd[8];
    int n = blockIdx.x, t = threadIdx.x;
    int deg = counts[n], start = offsets[n];
    if (t < 8) { rm[t] = -INFINITY; rl[t] = 0.f; sd[t] = s1[n * 16 + 8 + t]; }
    __syncthreads();
    float acc[8] = {};
    for (int e0 = 0; e0 < deg; e0 += CH) {
        int ch = min(CH, deg - e0);
        int items = ch * 8;
        for (int idx = t; idx < items; idx += 256) {
            int e = idx >> 3, h = idx & 7;
            int sn = elist[start + e0 + e];
            if (h == 0) sl[e] = sn;
            float sc = s1[sn * 16 + h] + sd[h];
            sc = (sc > 0.f) ? sc : 0.2f * sc;
            p[idx] = sc;
        }
        __syncthreads();
        {
            int h = t & 7;
            float mloc = -INFINITY;
            for (int e = t >> 3; e < ch; e += 32) mloc = fmaxf(mloc, p[e * 8 + h]);
            #pragma unroll
            for (int off = 8; off <= 32; off <<= 1) mloc = fmaxf(mloc, __shfl_xor(mloc, off, 64));
            if ((t & 63) < 8) sred[t >> 6][t & 7] = mloc;
        }
        __syncthreads();
        if (t < 8) {
            float cm = fmaxf(fmaxf(sred[0][t], sred[1][t]), fmaxf(sred[2][t], sred[3][t]));
            float mnew = fmaxf(rm[t], cm);
            float sc_ = exp2f((rm[t] - mnew) * LOG2E);
            sscale[t] = sc_;
            rm[t] = mnew;
            rl[t] *= sc_;
        }
        __syncthreads();
        #pragma unroll
        for (int h = 0; h < 8; h++) acc[h] *= sscale[h];
        for (int idx = t; idx < items; idx += 256) {
            int h = idx & 7;
            p[idx] = exp2f((p[idx] - rm[h]) * LOG2E);
        }
        __syncthreads();
        {
            int h = t & 7;
            float sloc = 0.f;
            for (int e = t >> 3; e < ch; e += 32) sloc += p[e * 8 + h];
            #pragma unroll
            for (int off = 8; off <= 32; off <<= 1) sloc += __shfl_xor(sloc, off, 64);
            if ((t & 63) < 8) sred[t >> 6][t & 7] = sloc;
        }
        __syncthreads();
        if (t < 8) rl[t] += sred[0][t] + sred[1][t] + sred[2][t] + sred[3][t];
        for (int e = 0; e < ch; e++) {
            int sn = sl[e];
            float v = hact[sn * 256 + t];
            #pragma unroll
            for (int h = 0; h < 8; h++) acc[h] += p[e * 8 + h] * v;
        }
        __syncthreads();
    }
    #pragma unroll
    for (int h = 0; h < 8; h++)
        aggout[(size_t)n * 2048 + h * 256 + t] = f2bf(acc[h] / rl[h]);
}

// W1pT bf16 [256][2048]: W1pT[c*2048 + h*256 + f] = W1[f*2048 + h*256 + c]
__global__ __launch_bounds__(256) void transpose_w1_kernel(
    const float* __restrict__ W1, short* __restrict__ W1pT)
{
    __shared__ float tile[32][33];
    int h = blockIdx.z;
    int f0 = blockIdx.x * 32, c0 = blockIdx.y * 32;
    int tx = threadIdx.x & 31, ty = threadIdx.x >> 5;  // 8 rows/iter
    for (int r = ty; r < 32; r += 8)
        tile[r][tx] = W1[(size_t)(f0 + r) * 2048 + h * 256 + c0 + tx];
    __syncthreads();
    for (int r = ty; r < 32; r += 8)
        W1pT[(size_t)(c0 + r) * 2048 + h * 256 + f0 + tx] = f2bf(tile[tx][r]);
}

// WcT bf16 [40][256]
__global__ void prep_wct_kernel(const float* __restrict__ Wc, short* __restrict__ WcT) {
    int o = blockIdx.x, t = threadIdx.x;
    WcT[o * 256 + t] = f2bf(Wc[t * 40 + o]);
}

// ---------------- batchnorm ----------------
__global__ __launch_bounds__(256) void bn_stats_kernel(const float* __restrict__ x, float* stats, int n) {
    int t = threadIdx.x;
    float s = 0.f, s2 = 0.f;
    for (int r = blockIdx.x; r < n; r += gridDim.x) {
        float v = x[(size_t)r * 256 + t];
        s += v; s2 += v * v;
    }
    atomicAdd(&stats[t], s);
    atomicAdd(&stats[256 + t], s2);
}

__global__ __launch_bounds__(256) void bn_apply_kernel(
    const float* __restrict__ x, const float* __restrict__ stats,
    const float* __restrict__ g, const float* __restrict__ be,
    const float* __restrict__ resid, float* __restrict__ y32,
    short* __restrict__ ybf, int total)
{
    int i = blockIdx.x * 256 + threadIdx.x;
    if (i >= total) return;
    int c = i & 255;
    const float invN = 1.0f / NN;
    float mu = stats[c] * invN;
    float var = stats[256 + c] * invN - mu * mu;
    float v = g[c] * (x[i] - mu) * rsqrtf(var + 1e-5f) + be[c];
    v = (v > 0.f) ? v : (expf(v) - 1.f);   // ELU
    if (resid) v += resid[i];
    if (y32) y32[i] = v;
    if (ybf) ybf[i] = f2bf(v);
}

// ---------------- launch ----------------
extern "C" void kernel_launch(void* const* d_in, const int* in_sizes, int n_in,
                              void* d_out, int out_size, void* d_ws, size_t ws_size,
                              hipStream_t stream) {
    const float* x      = (const float*)d_in[0];
    const int*   eidx   = (const int*)d_in[1];
    const float* W0     = (const float*)d_in[2];
    const float* a_src0 = (const float*)d_in[3];
    const float* a_dst0 = (const float*)d_in[4];
    const float* b0     = (const float*)d_in[5];
    const float* g0     = (const float*)d_in[6];
    const float* be0    = (const float*)d_in[7];
    const float* W1     = (const float*)d_in[8];
    const float* a_src1 = (const float*)d_in[9];
    const float* a_dst1 = (const float*)d_in[10];
    const float* b1     = (const float*)d_in[11];
    const float* g1     = (const float*)d_in[12];
    const float* be1    = (const float*)d_in[13];
    const float* Wc     = (const float*)d_in[14];
    const float* bc     = (const float*)d_in[15];
    float* out = (float*)d_out;

    const int E = in_sizes[1] / 2;
    const int* esrc = eidx;
    const int* edst = eidx + E;

    char* ws = (char*)d_ws;
    size_t off = 0;
    auto alloc = [&](size_t bytes) {
        void* p = ws + off;
        off += (bytes + 255) & ~(size_t)255;
        return p;
    };
    float* buf0    = (float*)alloc((size_t)NN * 256 * 4);   // h0, later out1
    float* s0      = (float*)alloc((size_t)NN * 16 * 4);
    float* s1      = (float*)alloc((size_t)NN * 16 * 4);
    float* v1      = (float*)alloc(4096 * 4);
    float* h_gat0  = (float*)alloc((size_t)NN * 256 * 4);
    float* hact    = (float*)alloc((size_t)NN * 256 * 4);
    short* agg1bf  = (short*)alloc((size_t)NN * 2048 * 2);
    short* W1pT    = (short*)alloc((size_t)256 * 2048 * 2);
    short* WcT     = (short*)alloc((size_t)64 * 256 * 2);
    short* hfinbf  = (short*)alloc((size_t)NN * 256 * 2);
    float* stats   = (float*)alloc(1024 * 4);
    int* counts    = (int*)alloc(NN * 4);
    int* offsets   = (int*)alloc((NN + 16) * 4);
    int* cursor    = (int*)alloc(NN * 4);
    int* elist     = (int*)alloc((size_t)(E + NN) * 4);

    float* h0     = buf0;
    float* out1   = buf0;
    float* stats0 = stats;
    float* stats1 = stats + 512;

    hipMemsetAsync(stats, 0, 1024 * 4, stream);

    // CSR build
    init_counts_kernel<<<(NN + 255) / 256, 256, 0, stream>>>(counts, NN);
    count_edges_kernel<<<(E + 255) / 256, 256, 0, stream>>>(edst, counts, E);
    scan_kernel<<<1, 1024, 0, stream>>>(counts, offsets, cursor, elist, NN);
    scatter_edges_kernel<<<(E + 255) / 256, 256, 0, stream>>>(esrc, edst, cursor, elist, E);

    // small precomputes
    prep_v1_kernel<<<16, 256, 0, stream>>>(W1, a_src1, a_dst1, v1);
    transpose_w1_kernel<<<dim3(8, 8, 8), 256, 0, stream>>>(W1, W1pT);
    prep_wct_kernel<<<NCLS, 256, 0, stream>>>(Wc, WcT);

    // layer 0 (fp32 GEMM kept as precision hedge on raw input x)
    {
        dim3 grid((NN + 63) / 64, (256 + 63) / 64);
        gemm_kernel<<<grid, 256, 0, stream>>>(x, W0, h0, nullptr, NN, 256, 256, 1.0f);
    }
    score0_kernel<<<NN, 256, 0, stream>>>(h0, a_src0, a_dst0, s0);
    agg0_kernel<<<NN, 256, 0, stream>>>(h0, s0, offsets, counts, elist, b0, h_gat0);
    bn_stats_kernel<<<128, 256, 0, stream>>>(h_gat0, stats0, NN);
    bn_apply_kernel<<<(NN * 256 + 255) / 256, 256, 0, stream>>>(
        h_gat0, stats0, g0, be0, nullptr, hact, nullptr, NN * 256);

    // layer 1
    score1_kernel<<<NN, 256, 0, stream>>>(hact, v1, s1);
    agg1_kernel<<<NN, 256, 0, stream>>>(hact, s1, offsets, counts, elist, agg1bf);
    {
        dim3 grid((NN + 127) / 128, 256 / 64);
        gemm_bf16_kernel<<<grid, 256, 0, stream>>>(agg1bf, W1pT, out1, b1, NN, 256, 2048, 0.125f);
    }
    bn_stats_kernel<<<128, 256, 0, stream>>>(out1, stats1, NN);
    bn_apply_kernel<<<(NN * 256 + 255) / 256, 256, 0, stream>>>(
        out1, stats1, g1, be1, hact, nullptr, hfinbf, NN * 256);

    // classifier (bf16 MFMA)
    {
        dim3 grid((NN + 127) / 128, 1);
        gemm_bf16_kernel<<<grid, 256, 0, stream>>>(hfinbf, WcT, out, bc, NN, NCLS, 256, 1.0f);
    }
}

// Round 3
// 346.586 us; speedup vs baseline: 1.8451x; 1.1884x over previous
//
#include <hip/hip_runtime.h>
#include <math.h>

#define NN 10000
#define HEADS 8
#define NCLS 40
#define CH 512
#define LOG2E 1.4426950408889634f

typedef __attribute__((ext_vector_type(8))) short short8;
typedef __attribute__((ext_vector_type(4))) float floatx4;

static __device__ __forceinline__ short f2bf(float f) {
    unsigned u = __builtin_bit_cast(unsigned, f);
    unsigned r = (u + 0x7fff + ((u >> 16) & 1)) >> 16;
    return (short)r;
}
static __device__ __forceinline__ float bf2f(unsigned short u) {
    unsigned x = ((unsigned)u) << 16;
    return __builtin_bit_cast(float, x);
}
static __device__ __forceinline__ void gl2lds16(const void* g, void* l) {
    __builtin_amdgcn_global_load_lds(
        (const __attribute__((address_space(1))) unsigned int*)g,
        (__attribute__((address_space(3))) unsigned int*)l, 16, 0, 0);
}

// ---------------- bf16 MFMA GEMM v2: C[M,N] = alpha*A[M,K]@Bt[N,K]^T + bias ----------------
// BM=64, BN=64, BK=32; 256 threads = 4 waves; wave w owns cols [w*16, w*16+16).
// Unpadded [row][32] LDS tiles: required by global_load_lds (wave-uniform base +
// lane*16B) and the b128 fragment reads cover 1024 contiguous B -> conflict-free.
__global__ __launch_bounds__(256) void gemm_bf16_v2(
    const short* __restrict__ A, const short* __restrict__ Bt,
    float* __restrict__ C, short* __restrict__ Cbf, const float* __restrict__ bias,
    int M, int Nn, int K, float alpha)
{
    __shared__ short As[64 * 32];
    __shared__ short Bs[64 * 32];
    const int tid = threadIdx.x;
    const int w = tid >> 6, L = tid & 63;
    const int quad = L >> 4, lr = L & 15;
    const int col0 = blockIdx.x * 64, row0 = blockIdx.y * 64;

    // staging: wave w stages 16 rows of A-tile and 16 rows of B-tile.
    int arow = row0 + w * 16 + (L >> 2); if (arow > M - 1) arow = M - 1;
    int brow = col0 + w * 16 + (L >> 2); if (brow > Nn - 1) brow = Nn - 1;
    const short* agp = A + (size_t)arow * K + (L & 3) * 8;
    const short* bgp = Bt + (size_t)brow * K + (L & 3) * 8;
    short* alp = &As[w * 512];   // wave-uniform LDS base
    short* blp = &Bs[w * 512];

    floatx4 acc[4];
    const floatx4 zf = {0.f, 0.f, 0.f, 0.f};
    #pragma unroll
    for (int i = 0; i < 4; i++) acc[i] = zf;

    for (int k0 = 0; k0 < K; k0 += 32) {
        gl2lds16(agp + k0, alp);
        gl2lds16(bgp + k0, blp);
        __syncthreads();
        short8 bfr = *(const short8*)&Bs[(w * 16 + lr) * 32 + quad * 8];
        #pragma unroll
        for (int i = 0; i < 4; i++) {
            short8 afr = *(const short8*)&As[(i * 16 + lr) * 32 + quad * 8];
            acc[i] = __builtin_amdgcn_mfma_f32_16x16x32_bf16(afr, bfr, acc[i], 0, 0, 0);
        }
        __syncthreads();
    }
    const int ccol = col0 + w * 16 + lr;
    if (ccol < Nn) {
        float bv = bias ? bias[ccol] : 0.f;
        #pragma unroll
        for (int i = 0; i < 4; i++) {
            #pragma unroll
            for (int r = 0; r < 4; r++) {
                int crow = row0 + i * 16 + quad * 4 + r;
                if (crow < M) {
                    float v = alpha * acc[i][r] + bv;
                    if (C)   C[(size_t)crow * Nn + ccol] = v;
                    if (Cbf) Cbf[(size_t)crow * Nn + ccol] = f2bf(v);
                }
            }
        }
    }
}

// ---------------- CSR build ----------------
__global__ void init_counts_kernel(int* counts, int n) {
    int i = blockIdx.x * 256 + threadIdx.x;
    if (i < n) counts[i] = 1;
}

__global__ void count_edges_kernel(const int* __restrict__ dst, int* counts, int E) {
    int e = blockIdx.x * 256 + threadIdx.x;
    if (e < E) atomicAdd(&counts[dst[e]], 1);
}

// single-block shfl-based scan (2 barriers total)
__global__ __launch_bounds__(1024) void scan_kernel(
    const int* __restrict__ counts, int* offsets, int* cursor, int* elist, int n)
{
    const int P = (n + 1023) >> 10;
    __shared__ int wsum[16];
    int tid = threadIdx.x, lane = tid & 63, wid = tid >> 6;
    int base = tid * P;
    int local[16];
    int s = 0;
    for (int j = 0; j < P; j++) {
        int i = base + j;
        local[j] = s;
        s += (i < n) ? counts[i] : 0;
    }
    int inc = s;
    #pragma unroll
    for (int off = 1; off < 64; off <<= 1) {
        int tv = __shfl_up(inc, off, 64);
        if (lane >= off) inc += tv;
    }
    if (lane == 63) wsum[wid] = inc;
    __syncthreads();
    if (tid < 16) {
        int v = wsum[tid];
        int winc = v;
        #pragma unroll
        for (int off = 1; off < 16; off <<= 1) {
            int tv = __shfl_up(winc, off, 16);
            if (tid >= off) winc += tv;
        }
        wsum[tid] = winc - v;   // exclusive wave offset
    }
    __syncthreads();
    int excl = inc - s + wsum[wid];
    for (int j = 0; j < P; j++) {
        int i = base + j;
        if (i < n) {
            int o = excl + local[j];
            offsets[i] = o;
            elist[o] = i;       // self-loop in slot 0
            cursor[i] = o + 1;
        }
    }
}

__global__ void scatter_edges_kernel(const int* __restrict__ src, const int* __restrict__ dst,
                                     int* cursor, int* elist, int E) {
    int e = blockIdx.x * 256 + threadIdx.x;
    if (e < E) {
        int d = dst[e];
        int pos = atomicAdd(&cursor[d], 1);
        elist[pos] = src[e];
    }
}

// ---------------- attention scores ----------------
__global__ __launch_bounds__(256) void score0_kernel(
    const float* __restrict__ h0, const float* __restrict__ a_src,
    const float* __restrict__ a_dst, float* __restrict__ s0)
{
    int n = blockIdx.x, t = threadIdx.x;
    float v = h0[n * 256 + t];
    float ps = v * a_src[t];
    float pd = v * a_dst[t];
    #pragma unroll
    for (int off = 16; off >= 1; off >>= 1) {
        ps += __shfl_down(ps, off, 32);
        pd += __shfl_down(pd, off, 32);
    }
    if ((t & 31) == 0) {
        int h = t >> 5;
        s0[n * 16 + h] = ps;
        s0[n * 16 + 8 + h] = pd;
    }
}

__global__ void prep_v1_kernel(const float* __restrict__ W1, const float* __restrict__ a_src1,
                               const float* __restrict__ a_dst1, float* __restrict__ v1)
{
    int idx = blockIdx.x * 256 + threadIdx.x;
    if (idx >= 256 * 16) return;
    int f = idx >> 4, j = idx & 15;
    int h = j & 7;
    const float* a = (j < 8) ? a_src1 : a_dst1;
    float s = 0.f;
    for (int c = 0; c < 256; c++)
        s += W1[f * 2048 + h * 256 + c] * a[h * 256 + c];
    v1[idx] = s;
}

__global__ __launch_bounds__(256) void score1_kernel(
    const float* __restrict__ h, const float* __restrict__ v1, float* __restrict__ s1)
{
    __shared__ float row[256];
    __shared__ float part[16][17];
    int n = blockIdx.x, t = threadIdx.x;
    row[t] = h[n * 256 + t];
    __syncthreads();
    int j = t & 15, f0 = t >> 4;
    float p = 0.f;
    #pragma unroll
    for (int k = 0; k < 16; k++) {
        int f = f0 * 16 + k;
        p += row[f] * v1[f * 16 + j];
    }
    part[f0][j] = p;
    __syncthreads();
    if (t < 16) {
        float s = 0.f;
        #pragma unroll
        for (int k = 0; k < 16; k++) s += part[k][t];
        s1[n * 16 + t] = s;
    }
}

// ---------------- layer-0 aggregation (bf16 gather) ----------------
__global__ __launch_bounds__(256) void agg0_kernel(
    const unsigned short* __restrict__ h0b, const float* __restrict__ s0,
    const int* __restrict__ offsets, const int* __restrict__ counts,
    const int* __restrict__ elist, float* __restrict__ out)
{
    __shared__ float p[CH * 8];
    __shared__ int sl[CH];
    __shared__ float sred[4][8];
    __shared__ float rm[8], rl[8], sscale[8], sd[8];
    int n = blockIdx.x, t = threadIdx.x;
    int deg = counts[n], start = offsets[n];
    if (t < 8) { rm[t] = -INFINITY; rl[t] = 0.f; sd[t] = s0[n * 16 + 8 + t]; }
    __syncthreads();
    float acc = 0.f;
    int myh = t >> 5;
    for (int e0 = 0; e0 < deg; e0 += CH) {
        int ch = deg - e0; if (ch > CH) ch = CH;
        int items = ch * 8;
        for (int e = t; e < ch; e += 256) sl[e] = elist[start + e0 + e];
        __syncthreads();
        for (int idx = t; idx < items; idx += 256) {
            int e = idx >> 3, h = idx & 7;
            float sc = s0[sl[e] * 16 + h] + sd[h];
            sc = (sc > 0.f) ? sc : 0.2f * sc;
            p[idx] = sc;
        }
        __syncthreads();
        {
            int h = t & 7;
            float mloc = -INFINITY;
            for (int e = t >> 3; e < ch; e += 32) mloc = fmaxf(mloc, p[e * 8 + h]);
            #pragma unroll
            for (int off = 8; off <= 32; off <<= 1) mloc = fmaxf(mloc, __shfl_xor(mloc, off, 64));
            if ((t & 63) < 8) sred[t >> 6][t & 7] = mloc;
        }
        __syncthreads();
        if (t < 8) {
            float cm = fmaxf(fmaxf(sred[0][t], sred[1][t]), fmaxf(sred[2][t], sred[3][t]));
            float mnew = fmaxf(rm[t], cm);
            float sc_ = exp2f((rm[t] - mnew) * LOG2E);
            sscale[t] = sc_;
            rm[t] = mnew;
            rl[t] *= sc_;
        }
        __syncthreads();
        acc *= sscale[myh];
        for (int idx = t; idx < items; idx += 256) {
            int h = idx & 7;
            p[idx] = exp2f((p[idx] - rm[h]) * LOG2E);
        }
        __syncthreads();
        {
            int h = t & 7;
            float sloc = 0.f;
            for (int e = t >> 3; e < ch; e += 32) sloc += p[e * 8 + h];
            #pragma unroll
            for (int off = 8; off <= 32; off <<= 1) sloc += __shfl_xor(sloc, off, 64);
            if ((t & 63) < 8) sred[t >> 6][t & 7] = sloc;
        }
        __syncthreads();
        if (t < 8) rl[t] += sred[0][t] + sred[1][t] + sred[2][t] + sred[3][t];
        int e = 0;
        for (; e + 4 <= ch; e += 4) {
            int sn0 = sl[e], sn1 = sl[e + 1], sn2 = sl[e + 2], sn3 = sl[e + 3];
            float w0 = p[(e + 0) * 8 + myh], w1 = p[(e + 1) * 8 + myh];
            float w2 = p[(e + 2) * 8 + myh], w3 = p[(e + 3) * 8 + myh];
            float v0 = bf2f(h0b[sn0 * 256 + t]);
            float v1_ = bf2f(h0b[sn1 * 256 + t]);
            float v2 = bf2f(h0b[sn2 * 256 + t]);
            float v3 = bf2f(h0b[sn3 * 256 + t]);
            acc += w0 * v0 + w1 * v1_ + w2 * v2 + w3 * v3;
        }
        for (; e < ch; e++)
            acc += p[e * 8 + myh] * bf2f(h0b[sl[e] * 256 + t]);
        __syncthreads();
    }
    out[n * 256 + t] = acc / rl[myh];
}

// ---------------- layer-1 aggregation (bf16 gather, bf16 out) ----------------
__global__ __launch_bounds__(256) void agg1_kernel(
    const unsigned short* __restrict__ hb, const float* __restrict__ s1,
    const int* __restrict__ offsets, const int* __restrict__ counts,
    const int* __restrict__ elist, short* __restrict__ aggout)
{
    __shared__ float p[CH * 8];
    __shared__ int sl[CH];
    __shared__ float sred[4][8];
    __shared__ float rm[8], rl[8], sscale[8], sd[8];
    int n = blockIdx.x, t = threadIdx.x;
    int deg = counts[n], start = offsets[n];
    if (t < 8) { rm[t] = -INFINITY; rl[t] = 0.f; sd[t] = s1[n * 16 + 8 + t]; }
    __syncthreads();
    float acc[8] = {};
    for (int e0 = 0; e0 < deg; e0 += CH) {
        int ch = deg - e0; if (ch > CH) ch = CH;
        int items = ch * 8;
        for (int e = t; e < ch; e += 256) sl[e] = elist[start + e0 + e];
        __syncthreads();
        for (int idx = t; idx < items; idx += 256) {
            int e = idx >> 3, h = idx & 7;
            float sc = s1[sl[e] * 16 + h] + sd[h];
            sc = (sc > 0.f) ? sc : 0.2f * sc;
            p[idx] = sc;
        }
        __syncthreads();
        {
            int h = t & 7;
            float mloc = -INFINITY;
            for (int e = t >> 3; e < ch; e += 32) mloc = fmaxf(mloc, p[e * 8 + h]);
            #pragma unroll
            for (int off = 8; off <= 32; off <<= 1) mloc = fmaxf(mloc, __shfl_xor(mloc, off, 64));
            if ((t & 63) < 8) sred[t >> 6][t & 7] = mloc;
        }
        __syncthreads();
        if (t < 8) {
            float cm = fmaxf(fmaxf(sred[0][t], sred[1][t]), fmaxf(sred[2][t], sred[3][t]));
            float mnew = fmaxf(rm[t], cm);
            float sc_ = exp2f((rm[t] - mnew) * LOG2E);
            sscale[t] = sc_;
            rm[t] = mnew;
            rl[t] *= sc_;
        }
        __syncthreads();
        #pragma unroll
        for (int h = 0; h < 8; h++) acc[h] *= sscale[h];
        for (int idx = t; idx < items; idx += 256) {
            int h = idx & 7;
            p[idx] = exp2f((p[idx] - rm[h]) * LOG2E);
        }
        __syncthreads();
        {
            int h = t & 7;
            float sloc = 0.f;
            for (int e = t >> 3; e < ch; e += 32) sloc += p[e * 8 + h];
            #pragma unroll
            for (int off = 8; off <= 32; off <<= 1) sloc += __shfl_xor(sloc, off, 64);
            if ((t & 63) < 8) sred[t >> 6][t & 7] = sloc;
        }
        __syncthreads();
        if (t < 8) rl[t] += sred[0][t] + sred[1][t] + sred[2][t] + sred[3][t];
        int e = 0;
        for (; e + 2 <= ch; e += 2) {
            int sn0 = sl[e], sn1 = sl[e + 1];
            float v0 = bf2f(hb[sn0 * 256 + t]);
            float v1_ = bf2f(hb[sn1 * 256 + t]);
            #pragma unroll
            for (int h = 0; h < 8; h++)
                acc[h] += p[e * 8 + h] * v0 + p[(e + 1) * 8 + h] * v1_;
        }
        for (; e < ch; e++) {
            float v = bf2f(hb[sl[e] * 256 + t]);
            #pragma unroll
            for (int h = 0; h < 8; h++) acc[h] += p[e * 8 + h] * v;
        }
        __syncthreads();
    }
    #pragma unroll
    for (int h = 0; h < 8; h++)
        aggout[(size_t)n * 2048 + h * 256 + t] = f2bf(acc[h] / rl[h]);
}

// ---------------- weight prep ----------------
// W1pT bf16 [256 c][2048 hf]: W1pT[c*2048 + h*256 + f] = W1[f*2048 + h*256 + c]
__global__ __launch_bounds__(256) void transpose_w1_kernel(
    const float* __restrict__ W1, short* __restrict__ W1pT)
{
    __shared__ float tile[32][33];
    int h = blockIdx.z;
    int f0 = blockIdx.x * 32, c0 = blockIdx.y * 32;
    int tx = threadIdx.x & 31, ty = threadIdx.x >> 5;
    for (int r = ty; r < 32; r += 8)
        tile[r][tx] = W1[(size_t)(f0 + r) * 2048 + h * 256 + c0 + tx];
    __syncthreads();
    for (int r = ty; r < 32; r += 8)
        W1pT[(size_t)(c0 + r) * 2048 + h * 256 + f0 + tx] = f2bf(tile[tx][r]);
}

__global__ void prep_wct_kernel(const float* __restrict__ Wc, short* __restrict__ WcT) {
    int o = blockIdx.x, t = threadIdx.x;
    WcT[o * 256 + t] = f2bf(Wc[t * 40 + o]);
}

__global__ void prep_w0t_kernel(const float* __restrict__ W0, short* __restrict__ W0T) {
    int o = blockIdx.x, t = threadIdx.x;
    W0T[o * 256 + t] = f2bf(W0[t * 256 + o]);
}

__global__ void cast_bf16_kernel(const float* __restrict__ in, short* __restrict__ out, int n) {
    int i = blockIdx.x * 256 + threadIdx.x;
    if (i < n) out[i] = f2bf(in[i]);
}

// ---------------- batchnorm ----------------
__global__ __launch_bounds__(256) void bn_stats_kernel(const float* __restrict__ x, float* stats, int n) {
    int t = threadIdx.x;
    float s = 0.f, s2 = 0.f;
    for (int r = blockIdx.x; r < n; r += gridDim.x) {
        float v = x[(size_t)r * 256 + t];
        s += v; s2 += v * v;
    }
    atomicAdd(&stats[t], s);
    atomicAdd(&stats[256 + t], s2);
}

__global__ __launch_bounds__(256) void bn_apply_kernel(
    const float* __restrict__ x, const float* __restrict__ stats,
    const float* __restrict__ g, const float* __restrict__ be,
    const float* __restrict__ resid, float* __restrict__ y32,
    short* __restrict__ ybf, int total)
{
    int i = blockIdx.x * 256 + threadIdx.x;
    if (i >= total) return;
    int c = i & 255;
    const float invN = 1.0f / NN;
    float mu = stats[c] * invN;
    float var = stats[256 + c] * invN - mu * mu;
    float v = g[c] * (x[i] - mu) * rsqrtf(var + 1e-5f) + be[c];
    v = (v > 0.f) ? v : (expf(v) - 1.f);   // ELU
    if (resid) v += resid[i];
    if (y32) y32[i] = v;
    if (ybf) ybf[i] = f2bf(v);
}

// ---------------- launch ----------------
extern "C" void kernel_launch(void* const* d_in, const int* in_sizes, int n_in,
                              void* d_out, int out_size, void* d_ws, size_t ws_size,
                              hipStream_t stream) {
    const float* x      = (const float*)d_in[0];
    const int*   eidx   = (const int*)d_in[1];
    const float* W0     = (const float*)d_in[2];
    const float* a_src0 = (const float*)d_in[3];
    const float* a_dst0 = (const float*)d_in[4];
    // d_in[5] = b0: cancels in BatchNorm (per-channel shift), dropped
    const float* g0     = (const float*)d_in[6];
    const float* be0    = (const float*)d_in[7];
    const float* W1     = (const float*)d_in[8];
    const float* a_src1 = (const float*)d_in[9];
    const float* a_dst1 = (const float*)d_in[10];
    // d_in[11] = b1: cancels in BatchNorm, dropped
    const float* g1     = (const float*)d_in[12];
    const float* be1    = (const float*)d_in[13];
    const float* Wc     = (const float*)d_in[14];
    const float* bc     = (const float*)d_in[15];
    float* out = (float*)d_out;

    const int E = in_sizes[1] / 2;
    const int* esrc = eidx;
    const int* edst = eidx + E;

    char* ws = (char*)d_ws;
    size_t off = 0;
    auto alloc = [&](size_t bytes) {
        void* p = ws + off;
        off += (bytes + 255) & ~(size_t)255;
        return p;
    };
    float* buf0    = (float*)alloc((size_t)NN * 256 * 4);   // h0, later out1
    short* h0b     = (short*)alloc((size_t)NN * 256 * 2);
    short* xb      = (short*)alloc((size_t)NN * 256 * 2);
    float* s0      = (float*)alloc((size_t)NN * 16 * 4);
    float* s1      = (float*)alloc((size_t)NN * 16 * 4);
    float* v1      = (float*)alloc(4096 * 4);
    float* h_gat0  = (float*)alloc((size_t)NN * 256 * 4);
    float* hact    = (float*)alloc((size_t)NN * 256 * 4);
    short* hactb   = (short*)alloc((size_t)NN * 256 * 2);
    short* agg1bf  = (short*)alloc((size_t)NN * 2048 * 2);
    short* W0T     = (short*)alloc((size_t)256 * 256 * 2);
    short* W1pT    = (short*)alloc((size_t)256 * 2048 * 2);
    short* WcT     = (short*)alloc((size_t)64 * 256 * 2);
    short* hfinbf  = (short*)alloc((size_t)NN * 256 * 2);
    float* stats   = (float*)alloc(1024 * 4);
    int* counts    = (int*)alloc(NN * 4);
    int* offsets   = (int*)alloc((NN + 16) * 4);
    int* cursor    = (int*)alloc(NN * 4);
    int* elist     = (int*)alloc((size_t)(E + NN) * 4);

    float* h0     = buf0;
    float* out1   = buf0;
    float* stats0 = stats;
    float* stats1 = stats + 512;

    hipMemsetAsync(stats, 0, 1024 * 4, stream);

    // CSR build
    init_counts_kernel<<<(NN + 255) / 256, 256, 0, stream>>>(counts, NN);
    count_edges_kernel<<<(E + 255) / 256, 256, 0, stream>>>(edst, counts, E);
    scan_kernel<<<1, 1024, 0, stream>>>(counts, offsets, cursor, elist, NN);
    scatter_edges_kernel<<<(E + 255) / 256, 256, 0, stream>>>(esrc, edst, cursor, elist, E);

    // precomputes
    cast_bf16_kernel<<<(NN * 256 + 255) / 256, 256, 0, stream>>>(x, xb, NN * 256);
    prep_w0t_kernel<<<256, 256, 0, stream>>>(W0, W0T);
    prep_v1_kernel<<<16, 256, 0, stream>>>(W1, a_src1, a_dst1, v1);
    transpose_w1_kernel<<<dim3(8, 8, 8), 256, 0, stream>>>(W1, W1pT);
    prep_wct_kernel<<<NCLS, 256, 0, stream>>>(Wc, WcT);

    // layer 0
    {
        dim3 grid(4, (NN + 63) / 64);
        gemm_bf16_v2<<<grid, 256, 0, stream>>>(xb, W0T, h0, h0b, nullptr, NN, 256, 256, 1.0f);
    }
    score0_kernel<<<NN, 256, 0, stream>>>(h0, a_src0, a_dst0, s0);
    agg0_kernel<<<NN, 256, 0, stream>>>((const unsigned short*)h0b, s0, offsets, counts, elist, h_gat0);
    bn_stats_kernel<<<128, 256, 0, stream>>>(h_gat0, stats0, NN);
    bn_apply_kernel<<<(NN * 256 + 255) / 256, 256, 0, stream>>>(
        h_gat0, stats0, g0, be0, nullptr, hact, hactb, NN * 256);

    // layer 1
    score1_kernel<<<NN, 256, 0, stream>>>(hact, v1, s1);
    agg1_kernel<<<NN, 256, 0, stream>>>((const unsigned short*)hactb, s1, offsets, counts, elist, agg1bf);
    {
        dim3 grid(4, (NN + 63) / 64);
        gemm_bf16_v2<<<grid, 256, 0, stream>>>(agg1bf, W1pT, out1, nullptr, nullptr, NN, 256, 2048, 0.125f);
    }
    bn_stats_kernel<<<128, 256, 0, stream>>>(out1, stats1, NN);
    bn_apply_kernel<<<(NN * 256 + 255) / 256, 256, 0, stream>>>(
        out1, stats1, g1, be1, hact, nullptr, hfinbf, NN * 256);

    // classifier
    {
        dim3 grid(1, (NN + 63) / 64);
        gemm_bf16_v2<<<grid, 256, 0, stream>>>(hfinbf, WcT, out, nullptr, bc, NN, NCLS, 256, 1.0f);
    }
}

// Round 4
// 328.734 us; speedup vs baseline: 1.9453x; 1.0543x over previous
//
#include <hip/hip_runtime.h>
#include <math.h>

#define NN 10000
#define HEADS 8
#define NCLS 40
#define CHK 64
#define LOG2E 1.4426950408889634f

typedef __attribute__((ext_vector_type(8))) short short8;
typedef __attribute__((ext_vector_type(4))) float floatx4;

static __device__ __forceinline__ short f2bf(float f) {
    unsigned u = __builtin_bit_cast(unsigned, f);
    unsigned r = (u + 0x7fff + ((u >> 16) & 1)) >> 16;
    return (short)r;
}
static __device__ __forceinline__ float bf2f(unsigned short u) {
    unsigned x = ((unsigned)u) << 16;
    return __builtin_bit_cast(float, x);
}
static __device__ __forceinline__ void gl2lds16(const void* g, void* l) {
    __builtin_amdgcn_global_load_lds(
        (const __attribute__((address_space(1))) unsigned int*)g,
        (__attribute__((address_space(3))) unsigned int*)l, 16, 0, 0);
}

// ---------------- bf16 MFMA GEMM: C[M,N] = alpha*A[M,K]@Bt[N,K]^T + bias ----------------
__global__ __launch_bounds__(256) void gemm_bf16_v2(
    const short* __restrict__ A, const short* __restrict__ Bt,
    float* __restrict__ C, short* __restrict__ Cbf, const float* __restrict__ bias,
    int M, int Nn, int K, float alpha)
{
    __shared__ short As[64 * 32];
    __shared__ short Bs[64 * 32];
    const int tid = threadIdx.x;
    const int w = tid >> 6, L = tid & 63;
    const int quad = L >> 4, lr = L & 15;
    const int col0 = blockIdx.x * 64, row0 = blockIdx.y * 64;

    int arow = row0 + w * 16 + (L >> 2); if (arow > M - 1) arow = M - 1;
    int brow = col0 + w * 16 + (L >> 2); if (brow > Nn - 1) brow = Nn - 1;
    const short* agp = A + (size_t)arow * K + (L & 3) * 8;
    const short* bgp = Bt + (size_t)brow * K + (L & 3) * 8;
    short* alp = &As[w * 512];
    short* blp = &Bs[w * 512];

    floatx4 acc[4];
    const floatx4 zf = {0.f, 0.f, 0.f, 0.f};
    #pragma unroll
    for (int i = 0; i < 4; i++) acc[i] = zf;

    for (int k0 = 0; k0 < K; k0 += 32) {
        gl2lds16(agp + k0, alp);
        gl2lds16(bgp + k0, blp);
        __syncthreads();
        short8 bfr = *(const short8*)&Bs[(w * 16 + lr) * 32 + quad * 8];
        #pragma unroll
        for (int i = 0; i < 4; i++) {
            short8 afr = *(const short8*)&As[(i * 16 + lr) * 32 + quad * 8];
            acc[i] = __builtin_amdgcn_mfma_f32_16x16x32_bf16(afr, bfr, acc[i], 0, 0, 0);
        }
        __syncthreads();
    }
    const int ccol = col0 + w * 16 + lr;
    if (ccol < Nn) {
        float bv = bias ? bias[ccol] : 0.f;
        #pragma unroll
        for (int i = 0; i < 4; i++) {
            #pragma unroll
            for (int r = 0; r < 4; r++) {
                int crow = row0 + i * 16 + quad * 4 + r;
                if (crow < M) {
                    float v = alpha * acc[i][r] + bv;
                    if (C)   C[(size_t)crow * Nn + ccol] = v;
                    if (Cbf) Cbf[(size_t)crow * Nn + ccol] = f2bf(v);
                }
            }
        }
    }
}

// ---------------- CSR build ----------------
__global__ void init_counts_kernel(int* counts, int n) {
    int i = blockIdx.x * 256 + threadIdx.x;
    if (i < n) counts[i] = 1;
}

__global__ void count_edges_kernel(const int* __restrict__ dst, int* counts, int E) {
    int e = blockIdx.x * 256 + threadIdx.x;
    if (e < E) atomicAdd(&counts[dst[e]], 1);
}

__global__ __launch_bounds__(1024) void scan_kernel(
    const int* __restrict__ counts, int* offsets, int* cursor, int* elist, int n)
{
    const int P = (n + 1023) >> 10;
    __shared__ int wsum[16];
    int tid = threadIdx.x, lane = tid & 63, wid = tid >> 6;
    int base = tid * P;
    int local[16];
    int s = 0;
    for (int j = 0; j < P; j++) {
        int i = base + j;
        local[j] = s;
        s += (i < n) ? counts[i] : 0;
    }
    int inc = s;
    #pragma unroll
    for (int off = 1; off < 64; off <<= 1) {
        int tv = __shfl_up(inc, off, 64);
        if (lane >= off) inc += tv;
    }
    if (lane == 63) wsum[wid] = inc;
    __syncthreads();
    if (tid < 16) {
        int v = wsum[tid];
        int winc = v;
        #pragma unroll
        for (int off = 1; off < 16; off <<= 1) {
            int tv = __shfl_up(winc, off, 16);
            if (tid >= off) winc += tv;
        }
        wsum[tid] = winc - v;
    }
    __syncthreads();
    int excl = inc - s + wsum[wid];
    for (int j = 0; j < P; j++) {
        int i = base + j;
        if (i < n) {
            int o = excl + local[j];
            offsets[i] = o;
            elist[o] = i;       // self-loop in slot 0
            cursor[i] = o + 1;
        }
    }
}

__global__ void scatter_edges_kernel(const int* __restrict__ src, const int* __restrict__ dst,
                                     int* cursor, int* elist, int E) {
    int e = blockIdx.x * 256 + threadIdx.x;
    if (e < E) {
        int d = dst[e];
        int pos = atomicAdd(&cursor[d], 1);
        elist[pos] = src[e];
    }
}

// ---------------- attention scores ----------------
__global__ __launch_bounds__(256) void score0_kernel(
    const float* __restrict__ h0, const float* __restrict__ a_src,
    const float* __restrict__ a_dst, float* __restrict__ s0)
{
    int n = blockIdx.x, t = threadIdx.x;
    float v = h0[n * 256 + t];
    float ps = v * a_src[t];
    float pd = v * a_dst[t];
    #pragma unroll
    for (int off = 16; off >= 1; off >>= 1) {
        ps += __shfl_down(ps, off, 32);
        pd += __shfl_down(pd, off, 32);
    }
    if ((t & 31) == 0) {
        int h = t >> 5;
        s0[n * 16 + h] = ps;
        s0[n * 16 + 8 + h] = pd;
    }
}

__global__ void prep_v1_kernel(const float* __restrict__ W1, const float* __restrict__ a_src1,
                               const float* __restrict__ a_dst1, float* __restrict__ v1)
{
    int idx = blockIdx.x * 256 + threadIdx.x;
    if (idx >= 256 * 16) return;
    int f = idx >> 4, j = idx & 15;
    int h = j & 7;
    const float* a = (j < 8) ? a_src1 : a_dst1;
    float s = 0.f;
    for (int c = 0; c < 256; c++)
        s += W1[f * 2048 + h * 256 + c] * a[h * 256 + c];
    v1[idx] = s;
}

__global__ __launch_bounds__(256) void score1_kernel(
    const float* __restrict__ h, const float* __restrict__ v1, float* __restrict__ s1)
{
    __shared__ float row[256];
    __shared__ float part[16][17];
    int n = blockIdx.x, t = threadIdx.x;
    row[t] = h[n * 256 + t];
    __syncthreads();
    int j = t & 15, f0 = t >> 4;
    float p = 0.f;
    #pragma unroll
    for (int k = 0; k < 16; k++) {
        int f = f0 * 16 + k;
        p += row[f] * v1[f * 16 + j];
    }
    part[f0][j] = p;
    __syncthreads();
    if (t < 16) {
        float s = 0.f;
        #pragma unroll
        for (int k = 0; k < 16; k++) s += part[k][t];
        s1[n * 16 + t] = s;
    }
}

// ---------------- layer-0 aggregation: wave-per-node, no barriers ----------------
// 4 nodes/block (one per wave). Lane L owns feats 4L..4L+3 (head = L>>3).
__global__ __launch_bounds__(256) void agg0_wave(
    const unsigned short* __restrict__ h0b, const float* __restrict__ s0,
    const int* __restrict__ offsets, const int* __restrict__ counts,
    const int* __restrict__ elist, float* __restrict__ out)
{
    __shared__ float pbuf[4][CHK * 8];
    __shared__ int   snbuf[4][CHK];
    const int wid = threadIdx.x >> 6, L = threadIdx.x & 63;
    const int n = blockIdx.x * 4 + wid;
    if (n >= NN) return;
    float* pw = pbuf[wid];
    int*   sw = snbuf[wid];
    const int deg = counts[n], start = offsets[n];
    const int hL = L >> 3;

    floatx4 sda = *(const floatx4*)(s0 + n * 16 + 8);
    floatx4 sdb = *(const floatx4*)(s0 + n * 16 + 12);
    float sd[8] = {sda[0], sda[1], sda[2], sda[3], sdb[0], sdb[1], sdb[2], sdb[3]};
    float rm[8], rl[8];
    #pragma unroll
    for (int h = 0; h < 8; h++) { rm[h] = -INFINITY; rl[h] = 0.f; }
    float acc[4] = {0.f, 0.f, 0.f, 0.f};

    for (int e0 = 0; e0 < deg; e0 += CHK) {
        int ch = deg - e0; if (ch > CHK) ch = CHK;
        int sn = 0;
        if (L < ch) sn = elist[start + e0 + L];
        sw[L] = sn;
        floatx4 ssa = *(const floatx4*)(s0 + sn * 16);
        floatx4 ssb = *(const floatx4*)(s0 + sn * 16 + 4);
        float sc[8] = {ssa[0], ssa[1], ssa[2], ssa[3], ssb[0], ssb[1], ssb[2], ssb[3]};
        #pragma unroll
        for (int h = 0; h < 8; h++) {
            float v = sc[h] + sd[h];
            v = (v > 0.f) ? v : 0.2f * v;
            sc[h] = (L < ch) ? v : -INFINITY;
        }
        float mx[8];
        #pragma unroll
        for (int h = 0; h < 8; h++) mx[h] = sc[h];
        #pragma unroll
        for (int off = 1; off < 64; off <<= 1)
            #pragma unroll
            for (int h = 0; h < 8; h++)
                mx[h] = fmaxf(mx[h], __shfl_xor(mx[h], off, 64));
        float scale[8], p[8];
        #pragma unroll
        for (int h = 0; h < 8; h++) {
            float mn = fmaxf(rm[h], mx[h]);
            scale[h] = exp2f((rm[h] - mn) * LOG2E);
            rm[h] = mn;
            p[h] = exp2f((sc[h] - mn) * LOG2E);   // -inf -> 0
        }
        float sm[8];
        #pragma unroll
        for (int h = 0; h < 8; h++) sm[h] = p[h];
        #pragma unroll
        for (int off = 1; off < 64; off <<= 1)
            #pragma unroll
            for (int h = 0; h < 8; h++)
                sm[h] += __shfl_xor(sm[h], off, 64);
        #pragma unroll
        for (int h = 0; h < 8; h++) rl[h] = rl[h] * scale[h] + sm[h];
        #pragma unroll
        for (int f = 0; f < 4; f++) acc[f] *= scale[hL];
        floatx4 p0 = {p[0], p[1], p[2], p[3]};
        floatx4 p1 = {p[4], p[5], p[6], p[7]};
        *(floatx4*)&pw[L * 8] = p0;
        *(floatx4*)&pw[L * 8 + 4] = p1;

        for (int e = 0; e < ch; e++) {
            int sne = sw[e];
            float wgt = pw[e * 8 + hL];
            ushort4 vv = *(const ushort4*)(h0b + (size_t)sne * 256 + 4 * L);
            acc[0] += wgt * bf2f(vv.x);
            acc[1] += wgt * bf2f(vv.y);
            acc[2] += wgt * bf2f(vv.z);
            acc[3] += wgt * bf2f(vv.w);
        }
    }
    float inv = 1.f / rl[hL];
    floatx4 o = {acc[0] * inv, acc[1] * inv, acc[2] * inv, acc[3] * inv};
    *(floatx4*)(out + (size_t)n * 256 + 4 * L) = o;
}

// ---------------- layer-1 aggregation: wave-per-node, all 8 heads/lane ----------------
__global__ __launch_bounds__(256) void agg1_wave(
    const unsigned short* __restrict__ hb, const float* __restrict__ s1,
    const int* __restrict__ offsets, const int* __restrict__ counts,
    const int* __restrict__ elist, short* __restrict__ aggout)
{
    __shared__ float pbuf[4][CHK * 8];
    __shared__ int   snbuf[4][CHK];
    const int wid = threadIdx.x >> 6, L = threadIdx.x & 63;
    const int n = blockIdx.x * 4 + wid;
    if (n >= NN) return;
    float* pw = pbuf[wid];
    int*   sw = snbuf[wid];
    const int deg = counts[n], start = offsets[n];

    floatx4 sda = *(const floatx4*)(s1 + n * 16 + 8);
    floatx4 sdb = *(const floatx4*)(s1 + n * 16 + 12);
    float sd[8] = {sda[0], sda[1], sda[2], sda[3], sdb[0], sdb[1], sdb[2], sdb[3]};
    float rm[8], rl[8];
    #pragma unroll
    for (int h = 0; h < 8; h++) { rm[h] = -INFINITY; rl[h] = 0.f; }
    float acc[8][4];
    #pragma unroll
    for (int h = 0; h < 8; h++)
        #pragma unroll
        for (int f = 0; f < 4; f++) acc[h][f] = 0.f;

    for (int e0 = 0; e0 < deg; e0 += CHK) {
        int ch = deg - e0; if (ch > CHK) ch = CHK;
        int sn = 0;
        if (L < ch) sn = elist[start + e0 + L];
        sw[L] = sn;
        floatx4 ssa = *(const floatx4*)(s1 + sn * 16);
        floatx4 ssb = *(const floatx4*)(s1 + sn * 16 + 4);
        float sc[8] = {ssa[0], ssa[1], ssa[2], ssa[3], ssb[0], ssb[1], ssb[2], ssb[3]};
        #pragma unroll
        for (int h = 0; h < 8; h++) {
            float v = sc[h] + sd[h];
            v = (v > 0.f) ? v : 0.2f * v;
            sc[h] = (L < ch) ? v : -INFINITY;
        }
        float mx[8];
        #pragma unroll
        for (int h = 0; h < 8; h++) mx[h] = sc[h];
        #pragma unroll
        for (int off = 1; off < 64; off <<= 1)
            #pragma unroll
            for (int h = 0; h < 8; h++)
                mx[h] = fmaxf(mx[h], __shfl_xor(mx[h], off, 64));
        float scale[8], p[8];
        #pragma unroll
        for (int h = 0; h < 8; h++) {
            float mn = fmaxf(rm[h], mx[h]);
            scale[h] = exp2f((rm[h] - mn) * LOG2E);
            rm[h] = mn;
            p[h] = exp2f((sc[h] - mn) * LOG2E);
        }
        float sm[8];
        #pragma unroll
        for (int h = 0; h < 8; h++) sm[h] = p[h];
        #pragma unroll
        for (int off = 1; off < 64; off <<= 1)
            #pragma unroll
            for (int h = 0; h < 8; h++)
                sm[h] += __shfl_xor(sm[h], off, 64);
        #pragma unroll
        for (int h = 0; h < 8; h++) rl[h] = rl[h] * scale[h] + sm[h];
        #pragma unroll
        for (int h = 0; h < 8; h++)
            #pragma unroll
            for (int f = 0; f < 4; f++) acc[h][f] *= scale[h];
        floatx4 p0 = {p[0], p[1], p[2], p[3]};
        floatx4 p1 = {p[4], p[5], p[6], p[7]};
        *(floatx4*)&pw[L * 8] = p0;
        *(floatx4*)&pw[L * 8 + 4] = p1;

        for (int e = 0; e < ch; e++) {
            int sne = sw[e];
            floatx4 pv0 = *(const floatx4*)&pw[e * 8];
            floatx4 pv1 = *(const floatx4*)&pw[e * 8 + 4];
            ushort4 vv = *(const ushort4*)(hb + (size_t)sne * 256 + 4 * L);
            float v0 = bf2f(vv.x), v1_ = bf2f(vv.y), v2 = bf2f(vv.z), v3 = bf2f(vv.w);
            #pragma unroll
            for (int h = 0; h < 4; h++) {
                acc[h][0] += pv0[h] * v0;
                acc[h][1] += pv0[h] * v1_;
                acc[h][2] += pv0[h] * v2;
                acc[h][3] += pv0[h] * v3;
                acc[h + 4][0] += pv1[h] * v0;
                acc[h + 4][1] += pv1[h] * v1_;
                acc[h + 4][2] += pv1[h] * v2;
                acc[h + 4][3] += pv1[h] * v3;
            }
        }
    }
    #pragma unroll
    for (int h = 0; h < 8; h++) {
        float inv = 1.f / rl[h];
        short4 o = {f2bf(acc[h][0] * inv), f2bf(acc[h][1] * inv),
                    f2bf(acc[h][2] * inv), f2bf(acc[h][3] * inv)};
        *(short4*)(aggout + (size_t)n * 2048 + h * 256 + 4 * L) = o;
    }
}

// ---------------- weight prep ----------------
__global__ __launch_bounds__(256) void transpose_w1_kernel(
    const float* __restrict__ W1, short* __restrict__ W1pT)
{
    __shared__ float tile[32][33];
    int h = blockIdx.z;
    int f0 = blockIdx.x * 32, c0 = blockIdx.y * 32;
    int tx = threadIdx.x & 31, ty = threadIdx.x >> 5;
    for (int r = ty; r < 32; r += 8)
        tile[r][tx] = W1[(size_t)(f0 + r) * 2048 + h * 256 + c0 + tx];
    __syncthreads();
    for (int r = ty; r < 32; r += 8)
        W1pT[(size_t)(c0 + r) * 2048 + h * 256 + f0 + tx] = f2bf(tile[tx][r]);
}

__global__ void prep_wct_kernel(const float* __restrict__ Wc, short* __restrict__ WcT) {
    int o = blockIdx.x, t = threadIdx.x;
    WcT[o * 256 + t] = f2bf(Wc[t * 40 + o]);
}

__global__ void prep_w0t_kernel(const float* __restrict__ W0, short* __restrict__ W0T) {
    int o = blockIdx.x, t = threadIdx.x;
    W0T[o * 256 + t] = f2bf(W0[t * 256 + o]);
}

__global__ void cast_bf16_kernel(const floatx4* __restrict__ in, short4* __restrict__ out, int n4) {
    int i = blockIdx.x * 256 + threadIdx.x;
    if (i < n4) {
        floatx4 v = in[i];
        short4 o = {f2bf(v[0]), f2bf(v[1]), f2bf(v[2]), f2bf(v[3])};
        out[i] = o;
    }
}

// ---------------- batchnorm ----------------
__global__ __launch_bounds__(256) void bn_stats_kernel(const float* __restrict__ x, float* stats, int n) {
    int t = threadIdx.x;
    float s = 0.f, s2 = 0.f;
    for (int r = blockIdx.x; r < n; r += gridDim.x) {
        float v = x[(size_t)r * 256 + t];
        s += v; s2 += v * v;
    }
    atomicAdd(&stats[t], s);
    atomicAdd(&stats[256 + t], s2);
}

__global__ __launch_bounds__(256) void bn_apply_kernel(
    const float* __restrict__ x, const float* __restrict__ stats,
    const float* __restrict__ g, const float* __restrict__ be,
    const float* __restrict__ resid, float* __restrict__ y32,
    short* __restrict__ ybf, int total)
{
    int i = blockIdx.x * 256 + threadIdx.x;
    if (i >= total) return;
    int c = i & 255;
    const float invN = 1.0f / NN;
    float mu = stats[c] * invN;
    float var = stats[256 + c] * invN - mu * mu;
    float v = g[c] * (x[i] - mu) * rsqrtf(var + 1e-5f) + be[c];
    v = (v > 0.f) ? v : (expf(v) - 1.f);   // ELU
    if (resid) v += resid[i];
    if (y32) y32[i] = v;
    if (ybf) ybf[i] = f2bf(v);
}

// ---------------- launch ----------------
extern "C" void kernel_launch(void* const* d_in, const int* in_sizes, int n_in,
                              void* d_out, int out_size, void* d_ws, size_t ws_size,
                              hipStream_t stream) {
    const float* x      = (const float*)d_in[0];
    const int*   eidx   = (const int*)d_in[1];
    const float* W0     = (const float*)d_in[2];
    const float* a_src0 = (const float*)d_in[3];
    const float* a_dst0 = (const float*)d_in[4];
    const float* g0     = (const float*)d_in[6];
    const float* be0    = (const float*)d_in[7];
    const float* W1     = (const float*)d_in[8];
    const float* a_src1 = (const float*)d_in[9];
    const float* a_dst1 = (const float*)d_in[10];
    const float* g1     = (const float*)d_in[12];
    const float* be1    = (const float*)d_in[13];
    const float* Wc     = (const float*)d_in[14];
    const float* bc     = (const float*)d_in[15];
    float* out = (float*)d_out;

    const int E = in_sizes[1] / 2;
    const int* esrc = eidx;
    const int* edst = eidx + E;

    char* ws = (char*)d_ws;
    size_t off = 0;
    auto alloc = [&](size_t bytes) {
        void* p = ws + off;
        off += (bytes + 255) & ~(size_t)255;
        return p;
    };
    float* buf0    = (float*)alloc((size_t)NN * 256 * 4);   // h0, later out1
    short* h0b     = (short*)alloc((size_t)NN * 256 * 2);
    short* xb      = (short*)alloc((size_t)NN * 256 * 2);
    float* s0      = (float*)alloc((size_t)NN * 16 * 4);
    float* s1      = (float*)alloc((size_t)NN * 16 * 4);
    float* v1      = (float*)alloc(4096 * 4);
    float* h_gat0  = (float*)alloc((size_t)NN * 256 * 4);
    float* hact    = (float*)alloc((size_t)NN * 256 * 4);
    short* hactb   = (short*)alloc((size_t)NN * 256 * 2);
    short* agg1bf  = (short*)alloc((size_t)NN * 2048 * 2);
    short* W0T     = (short*)alloc((size_t)256 * 256 * 2);
    short* W1pT    = (short*)alloc((size_t)256 * 2048 * 2);
    short* WcT     = (short*)alloc((size_t)64 * 256 * 2);
    short* hfinbf  = (short*)alloc((size_t)NN * 256 * 2);
    float* stats   = (float*)alloc(1024 * 4);
    int* counts    = (int*)alloc(NN * 4);
    int* offsets   = (int*)alloc((NN + 16) * 4);
    int* cursor    = (int*)alloc(NN * 4);
    int* elist     = (int*)alloc((size_t)(E + NN) * 4);

    float* h0     = buf0;
    float* out1   = buf0;
    float* stats0 = stats;
    float* stats1 = stats + 512;

    hipMemsetAsync(stats, 0, 1024 * 4, stream);

    // CSR build
    init_counts_kernel<<<(NN + 255) / 256, 256, 0, stream>>>(counts, NN);
    count_edges_kernel<<<(E + 255) / 256, 256, 0, stream>>>(edst, counts, E);
    scan_kernel<<<1, 1024, 0, stream>>>(counts, offsets, cursor, elist, NN);
    scatter_edges_kernel<<<(E + 255) / 256, 256, 0, stream>>>(esrc, edst, cursor, elist, E);

    // precomputes
    cast_bf16_kernel<<<(NN * 64 + 255) / 256, 256, 0, stream>>>(
        (const floatx4*)x, (short4*)xb, NN * 64);
    prep_w0t_kernel<<<256, 256, 0, stream>>>(W0, W0T);
    prep_v1_kernel<<<16, 256, 0, stream>>>(W1, a_src1, a_dst1, v1);
    transpose_w1_kernel<<<dim3(8, 8, 8), 256, 0, stream>>>(W1, W1pT);
    prep_wct_kernel<<<NCLS, 256, 0, stream>>>(Wc, WcT);

    // layer 0
    {
        dim3 grid(4, (NN + 63) / 64);
        gemm_bf16_v2<<<grid, 256, 0, stream>>>(xb, W0T, h0, h0b, nullptr, NN, 256, 256, 1.0f);
    }
    score0_kernel<<<NN, 256, 0, stream>>>(h0, a_src0, a_dst0, s0);
    agg0_wave<<<(NN + 3) / 4, 256, 0, stream>>>(
        (const unsigned short*)h0b, s0, offsets, counts, elist, h_gat0);
    bn_stats_kernel<<<256, 256, 0, stream>>>(h_gat0, stats0, NN);
    bn_apply_kernel<<<(NN * 256 + 255) / 256, 256, 0, stream>>>(
        h_gat0, stats0, g0, be0, nullptr, hact, hactb, NN * 256);

    // layer 1
    score1_kernel<<<NN, 256, 0, stream>>>(hact, v1, s1);
    agg1_wave<<<(NN + 3) / 4, 256, 0, stream>>>(
        (const unsigned short*)hactb, s1, offsets, counts, elist, agg1bf);
    {
        dim3 grid(4, (NN + 63) / 64);
        gemm_bf16_v2<<<grid, 256, 0, stream>>>(agg1bf, W1pT, out1, nullptr, nullptr, NN, 256, 2048, 0.125f);
    }
    bn_stats_kernel<<<256, 256, 0, stream>>>(out1, stats1, NN);
    bn_apply_kernel<<<(NN * 256 + 255) / 256, 256, 0, stream>>>(
        out1, stats1, g1, be1, hact, nullptr, hfinbf, NN * 256);

    // classifier
    {
        dim3 grid(1, (NN + 63) / 64);
        gemm_bf16_v2<<<grid, 256, 0, stream>>>(hfinbf, WcT, out, nullptr, bc, NN, NCLS, 256, 1.0f);
    }
}

// Round 5
// 315.181 us; speedup vs baseline: 2.0290x; 1.0430x over previous
//
#include <hip/hip_runtime.h>
#include <math.h>

#define NN 10000
#define HEADS 8
#define NCLS 40
#define CHK 64
#define LOG2E 1.4426950408889634f

typedef __attribute__((ext_vector_type(8))) short short8;
typedef __attribute__((ext_vector_type(4))) float floatx4;

static __device__ __forceinline__ short f2bf(float f) {
    unsigned u = __builtin_bit_cast(unsigned, f);
    unsigned r = (u + 0x7fff + ((u >> 16) & 1)) >> 16;
    return (short)r;
}
static __device__ __forceinline__ float bf2f(unsigned short u) {
    unsigned x = ((unsigned)u) << 16;
    return __builtin_bit_cast(float, x);
}
static __device__ __forceinline__ void gl2lds16(const void* g, void* l) {
    __builtin_amdgcn_global_load_lds(
        (const __attribute__((address_space(1))) unsigned int*)g,
        (__attribute__((address_space(3))) unsigned int*)l, 16, 0, 0);
}

// ---------------- bf16 MFMA GEMM: C[M,N] = alpha*A[M,K]@Bt[N,K]^T + bias ----------------
__global__ __launch_bounds__(256) void gemm_bf16_v2(
    const short* __restrict__ A, const short* __restrict__ Bt,
    float* __restrict__ C, short* __restrict__ Cbf, const float* __restrict__ bias,
    int M, int Nn, int K, float alpha)
{
    __shared__ short As[64 * 32];
    __shared__ short Bs[64 * 32];
    const int tid = threadIdx.x;
    const int w = tid >> 6, L = tid & 63;
    const int quad = L >> 4, lr = L & 15;
    const int col0 = blockIdx.x * 64, row0 = blockIdx.y * 64;

    int arow = row0 + w * 16 + (L >> 2); if (arow > M - 1) arow = M - 1;
    int brow = col0 + w * 16 + (L >> 2); if (brow > Nn - 1) brow = Nn - 1;
    const short* agp = A + (size_t)arow * K + (L & 3) * 8;
    const short* bgp = Bt + (size_t)brow * K + (L & 3) * 8;
    short* alp = &As[w * 512];
    short* blp = &Bs[w * 512];

    floatx4 acc[4];
    const floatx4 zf = {0.f, 0.f, 0.f, 0.f};
    #pragma unroll
    for (int i = 0; i < 4; i++) acc[i] = zf;

    for (int k0 = 0; k0 < K; k0 += 32) {
        gl2lds16(agp + k0, alp);
        gl2lds16(bgp + k0, blp);
        __syncthreads();
        short8 bfr = *(const short8*)&Bs[(w * 16 + lr) * 32 + quad * 8];
        #pragma unroll
        for (int i = 0; i < 4; i++) {
            short8 afr = *(const short8*)&As[(i * 16 + lr) * 32 + quad * 8];
            acc[i] = __builtin_amdgcn_mfma_f32_16x16x32_bf16(afr, bfr, acc[i], 0, 0, 0);
        }
        __syncthreads();
    }
    const int ccol = col0 + w * 16 + lr;
    if (ccol < Nn) {
        float bv = bias ? bias[ccol] : 0.f;
        #pragma unroll
        for (int i = 0; i < 4; i++) {
            #pragma unroll
            for (int r = 0; r < 4; r++) {
                int crow = row0 + i * 16 + quad * 4 + r;
                if (crow < M) {
                    float v = alpha * acc[i][r] + bv;
                    if (C)   C[(size_t)crow * Nn + ccol] = v;
                    if (Cbf) Cbf[(size_t)crow * Nn + ccol] = f2bf(v);
                }
            }
        }
    }
}

// ---------------- CSR build ----------------
__global__ void init_counts_kernel(int* counts, int n) {
    int i = blockIdx.x * 256 + threadIdx.x;
    if (i < n) counts[i] = 1;
}

__global__ void count_edges_kernel(const int* __restrict__ dst, int* counts, int E) {
    int e = blockIdx.x * 256 + threadIdx.x;
    if (e < E) atomicAdd(&counts[dst[e]], 1);
}

__global__ __launch_bounds__(1024) void scan_kernel(
    const int* __restrict__ counts, int* offsets, int* cursor, int* elist, int n)
{
    const int P = (n + 1023) >> 10;
    __shared__ int wsum[16];
    int tid = threadIdx.x, lane = tid & 63, wid = tid >> 6;
    int base = tid * P;
    int local[16];
    int s = 0;
    for (int j = 0; j < P; j++) {
        int i = base + j;
        local[j] = s;
        s += (i < n) ? counts[i] : 0;
    }
    int inc = s;
    #pragma unroll
    for (int off = 1; off < 64; off <<= 1) {
        int tv = __shfl_up(inc, off, 64);
        if (lane >= off) inc += tv;
    }
    if (lane == 63) wsum[wid] = inc;
    __syncthreads();
    if (tid < 16) {
        int v = wsum[tid];
        int winc = v;
        #pragma unroll
        for (int off = 1; off < 16; off <<= 1) {
            int tv = __shfl_up(winc, off, 16);
            if (tid >= off) winc += tv;
        }
        wsum[tid] = winc - v;
    }
    __syncthreads();
    int excl = inc - s + wsum[wid];
    for (int j = 0; j < P; j++) {
        int i = base + j;
        if (i < n) {
            int o = excl + local[j];
            offsets[i] = o;
            elist[o] = i;       // self-loop in slot 0
            cursor[i] = o + 1;
        }
    }
}

__global__ void scatter_edges_kernel(const int* __restrict__ src, const int* __restrict__ dst,
                                     int* cursor, int* elist, int E) {
    int e = blockIdx.x * 256 + threadIdx.x;
    if (e < E) {
        int d = dst[e];
        int pos = atomicAdd(&cursor[d], 1);
        elist[pos] = src[e];
    }
}

// ---------------- attention scores (from bf16 features) ----------------
__global__ __launch_bounds__(256) void score0_kernel(
    const unsigned short* __restrict__ h0b, const float* __restrict__ a_src,
    const float* __restrict__ a_dst, float* __restrict__ s0)
{
    int n = blockIdx.x, t = threadIdx.x;
    float v = bf2f(h0b[n * 256 + t]);
    float ps = v * a_src[t];
    float pd = v * a_dst[t];
    #pragma unroll
    for (int off = 16; off >= 1; off >>= 1) {
        ps += __shfl_down(ps, off, 32);
        pd += __shfl_down(pd, off, 32);
    }
    if ((t & 31) == 0) {
        int h = t >> 5;
        s0[n * 16 + h] = ps;
        s0[n * 16 + 8 + h] = pd;
    }
}

__global__ void prep_v1_kernel(const float* __restrict__ W1, const float* __restrict__ a_src1,
                               const float* __restrict__ a_dst1, float* __restrict__ v1)
{
    int idx = blockIdx.x * 256 + threadIdx.x;
    if (idx >= 256 * 16) return;
    int f = idx >> 4, j = idx & 15;
    int h = j & 7;
    const float* a = (j < 8) ? a_src1 : a_dst1;
    float s = 0.f;
    for (int c = 0; c < 256; c++)
        s += W1[f * 2048 + h * 256 + c] * a[h * 256 + c];
    v1[idx] = s;
}

__global__ __launch_bounds__(256) void score1_kernel(
    const unsigned short* __restrict__ hb, const float* __restrict__ v1, float* __restrict__ s1)
{
    __shared__ float row[256];
    __shared__ float part[16][17];
    int n = blockIdx.x, t = threadIdx.x;
    row[t] = bf2f(hb[n * 256 + t]);
    __syncthreads();
    int j = t & 15, f0 = t >> 4;
    float p = 0.f;
    #pragma unroll
    for (int k = 0; k < 16; k++) {
        int f = f0 * 16 + k;
        p += row[f] * v1[f * 16 + j];
    }
    part[f0][j] = p;
    __syncthreads();
    if (t < 16) {
        float s = 0.f;
        #pragma unroll
        for (int k = 0; k < 16; k++) s += part[k][t];
        s1[n * 16 + t] = s;
    }
}

// ---------------- p = exp(leakyrelu(score)) per CSR slot + per-(node,head) 1/sum ----------------
// No max-subtraction: scores are O(10) post-normalization, exp fine in fp32
// (mathematically identical to the reference's max-shifted softmax).
__global__ __launch_bounds__(256) void pden_wave(
    const float* __restrict__ s, const int* __restrict__ offsets,
    const int* __restrict__ counts, const int* __restrict__ elist,
    float* __restrict__ pbuf, float* __restrict__ dinv)
{
    const int wid = threadIdx.x >> 6, L = threadIdx.x & 63;
    const int n = blockIdx.x * 4 + wid;
    if (n >= NN) return;
    const int deg = counts[n], start = offsets[n];
    floatx4 sda = *(const floatx4*)(s + n * 16 + 8);
    floatx4 sdb = *(const floatx4*)(s + n * 16 + 12);
    float sd[8] = {sda[0], sda[1], sda[2], sda[3], sdb[0], sdb[1], sdb[2], sdb[3]};
    float l[8] = {0.f, 0.f, 0.f, 0.f, 0.f, 0.f, 0.f, 0.f};
    for (int e0 = 0; e0 < deg; e0 += CHK) {
        int ch = deg - e0; if (ch > CHK) ch = CHK;
        int sn = (L < ch) ? elist[start + e0 + L] : 0;
        floatx4 ssa = *(const floatx4*)(s + sn * 16);
        floatx4 ssb = *(const floatx4*)(s + sn * 16 + 4);
        float ss[8] = {ssa[0], ssa[1], ssa[2], ssa[3], ssb[0], ssb[1], ssb[2], ssb[3]};
        float p[8];
        #pragma unroll
        for (int h = 0; h < 8; h++) {
            float v = ss[h] + sd[h];
            v = (v > 0.f) ? v : 0.2f * v;
            p[h] = (L < ch) ? exp2f(v * LOG2E) : 0.f;
        }
        float sm[8];
        #pragma unroll
        for (int h = 0; h < 8; h++) sm[h] = p[h];
        #pragma unroll
        for (int off = 1; off < 64; off <<= 1)
            #pragma unroll
            for (int h = 0; h < 8; h++)
                sm[h] += __shfl_xor(sm[h], off, 64);
        #pragma unroll
        for (int h = 0; h < 8; h++) l[h] += sm[h];
        if (L < ch) {
            floatx4 p0 = {p[0], p[1], p[2], p[3]};
            floatx4 p1 = {p[4], p[5], p[6], p[7]};
            *(floatx4*)(pbuf + (size_t)(start + e0 + L) * 8) = p0;
            *(floatx4*)(pbuf + (size_t)(start + e0 + L) * 8 + 4) = p1;
        }
    }
    if (L == 0) {
        floatx4 d0 = {1.f / l[0], 1.f / l[1], 1.f / l[2], 1.f / l[3]};
        floatx4 d1 = {1.f / l[4], 1.f / l[5], 1.f / l[6], 1.f / l[7]};
        *(floatx4*)(dinv + n * 8) = d0;
        *(floatx4*)(dinv + n * 8 + 4) = d1;
    }
}

// ---------------- layer-0 aggregation: pure gather-FMA ----------------
__global__ __launch_bounds__(256) void agg0_wave(
    const unsigned short* __restrict__ h0b, const float* __restrict__ pbuf,
    const float* __restrict__ dinv, const int* __restrict__ offsets,
    const int* __restrict__ counts, const int* __restrict__ elist,
    float* __restrict__ out)
{
    __shared__ float pw_s[4][CHK * 8];
    __shared__ int   sn_s[4][CHK];
    const int wid = threadIdx.x >> 6, L = threadIdx.x & 63;
    const int n = blockIdx.x * 4 + wid;
    if (n >= NN) return;
    float* pw = pw_s[wid];
    int*   sw = sn_s[wid];
    const int deg = counts[n], start = offsets[n];
    const int hL = L >> 3;
    float acc0 = 0.f, acc1 = 0.f, acc2 = 0.f, acc3 = 0.f;

    for (int e0 = 0; e0 < deg; e0 += CHK) {
        int ch = deg - e0; if (ch > CHK) ch = CHK;
        if (L < ch) {
            sw[L] = elist[start + e0 + L];
            floatx4 p0 = *(const floatx4*)(pbuf + (size_t)(start + e0 + L) * 8);
            floatx4 p1 = *(const floatx4*)(pbuf + (size_t)(start + e0 + L) * 8 + 4);
            *(floatx4*)&pw[L * 8] = p0;
            *(floatx4*)&pw[L * 8 + 4] = p1;
        }
        for (int e = 0; e < ch; e++) {
            float wgt = pw[e * 8 + hL];
            ushort4 vv = *(const ushort4*)(h0b + (size_t)sw[e] * 256 + 4 * L);
            acc0 += wgt * bf2f(vv.x);
            acc1 += wgt * bf2f(vv.y);
            acc2 += wgt * bf2f(vv.z);
            acc3 += wgt * bf2f(vv.w);
        }
    }
    float inv = dinv[n * 8 + hL];
    floatx4 o = {acc0 * inv, acc1 * inv, acc2 * inv, acc3 * inv};
    *(floatx4*)(out + (size_t)n * 256 + 4 * L) = o;
}

// ---------------- layer-1 aggregation: pure gather-FMA, all 8 heads ----------------
__global__ __launch_bounds__(256) void agg1_wave(
    const unsigned short* __restrict__ hb, const float* __restrict__ pbuf,
    const float* __restrict__ dinv, const int* __restrict__ offsets,
    const int* __restrict__ counts, const int* __restrict__ elist,
    short* __restrict__ aggout)
{
    __shared__ float pw_s[4][CHK * 8];
    __shared__ int   sn_s[4][CHK];
    const int wid = threadIdx.x >> 6, L = threadIdx.x & 63;
    const int n = blockIdx.x * 4 + wid;
    if (n >= NN) return;
    float* pw = pw_s[wid];
    int*   sw = sn_s[wid];
    const int deg = counts[n], start = offsets[n];

    float acc[8][4];
    #pragma unroll
    for (int h = 0; h < 8; h++)
        #pragma unroll
        for (int f = 0; f < 4; f++) acc[h][f] = 0.f;

    for (int e0 = 0; e0 < deg; e0 += CHK) {
        int ch = deg - e0; if (ch > CHK) ch = CHK;
        if (L < ch) {
            sw[L] = elist[start + e0 + L];
            floatx4 p0 = *(const floatx4*)(pbuf + (size_t)(start + e0 + L) * 8);
            floatx4 p1 = *(const floatx4*)(pbuf + (size_t)(start + e0 + L) * 8 + 4);
            *(floatx4*)&pw[L * 8] = p0;
            *(floatx4*)&pw[L * 8 + 4] = p1;
        }
        for (int e = 0; e < ch; e++) {
            floatx4 pv0 = *(const floatx4*)&pw[e * 8];
            floatx4 pv1 = *(const floatx4*)&pw[e * 8 + 4];
            ushort4 vv = *(const ushort4*)(hb + (size_t)sw[e] * 256 + 4 * L);
            float v0 = bf2f(vv.x), v1_ = bf2f(vv.y), v2 = bf2f(vv.z), v3 = bf2f(vv.w);
            #pragma unroll
            for (int h = 0; h < 4; h++) {
                acc[h][0] += pv0[h] * v0;
                acc[h][1] += pv0[h] * v1_;
                acc[h][2] += pv0[h] * v2;
                acc[h][3] += pv0[h] * v3;
                acc[h + 4][0] += pv1[h] * v0;
                acc[h + 4][1] += pv1[h] * v1_;
                acc[h + 4][2] += pv1[h] * v2;
                acc[h + 4][3] += pv1[h] * v3;
            }
        }
    }
    floatx4 d0 = *(const floatx4*)(dinv + n * 8);
    floatx4 d1 = *(const floatx4*)(dinv + n * 8 + 4);
    #pragma unroll
    for (int h = 0; h < 8; h++) {
        float inv = (h < 4) ? d0[h] : d1[h - 4];
        short4 o = {f2bf(acc[h][0] * inv), f2bf(acc[h][1] * inv),
                    f2bf(acc[h][2] * inv), f2bf(acc[h][3] * inv)};
        *(short4*)(aggout + (size_t)n * 2048 + h * 256 + 4 * L) = o;
    }
}

// ---------------- weight prep ----------------
__global__ __launch_bounds__(256) void transpose_w1_kernel(
    const float* __restrict__ W1, short* __restrict__ W1pT)
{
    __shared__ float tile[32][33];
    int h = blockIdx.z;
    int f0 = blockIdx.x * 32, c0 = blockIdx.y * 32;
    int tx = threadIdx.x & 31, ty = threadIdx.x >> 5;
    for (int r = ty; r < 32; r += 8)
        tile[r][tx] = W1[(size_t)(f0 + r) * 2048 + h * 256 + c0 + tx];
    __syncthreads();
    for (int r = ty; r < 32; r += 8)
        W1pT[(size_t)(c0 + r) * 2048 + h * 256 + f0 + tx] = f2bf(tile[tx][r]);
}

__global__ void prep_wct_kernel(const float* __restrict__ Wc, short* __restrict__ WcT) {
    int o = blockIdx.x, t = threadIdx.x;
    WcT[o * 256 + t] = f2bf(Wc[t * 40 + o]);
}

__global__ void prep_w0t_kernel(const float* __restrict__ W0, short* __restrict__ W0T) {
    int o = blockIdx.x, t = threadIdx.x;
    W0T[o * 256 + t] = f2bf(W0[t * 256 + o]);
}

__global__ void cast_bf16_kernel(const floatx4* __restrict__ in, short4* __restrict__ out, int n4) {
    int i = blockIdx.x * 256 + threadIdx.x;
    if (i < n4) {
        floatx4 v = in[i];
        short4 o = {f2bf(v[0]), f2bf(v[1]), f2bf(v[2]), f2bf(v[3])};
        out[i] = o;
    }
}

// ---------------- batchnorm ----------------
__global__ __launch_bounds__(256) void bn_stats_kernel(const float* __restrict__ x, float* stats, int n) {
    int t = threadIdx.x;
    float s = 0.f, s2 = 0.f;
    for (int r = blockIdx.x; r < n; r += gridDim.x) {
        float v = x[(size_t)r * 256 + t];
        s += v; s2 += v * v;
    }
    atomicAdd(&stats[t], s);
    atomicAdd(&stats[256 + t], s2);
}

__global__ __launch_bounds__(256) void bn_apply_kernel(
    const float* __restrict__ x, const float* __restrict__ stats,
    const float* __restrict__ g, const float* __restrict__ be,
    const float* __restrict__ resid, float* __restrict__ y32,
    short* __restrict__ ybf, int total)
{
    int i = blockIdx.x * 256 + threadIdx.x;
    if (i >= total) return;
    int c = i & 255;
    const float invN = 1.0f / NN;
    float mu = stats[c] * invN;
    float var = stats[256 + c] * invN - mu * mu;
    float v = g[c] * (x[i] - mu) * rsqrtf(var + 1e-5f) + be[c];
    v = (v > 0.f) ? v : (expf(v) - 1.f);   // ELU
    if (resid) v += resid[i];
    if (y32) y32[i] = v;
    if (ybf) ybf[i] = f2bf(v);
}

// ---------------- launch ----------------
extern "C" void kernel_launch(void* const* d_in, const int* in_sizes, int n_in,
                              void* d_out, int out_size, void* d_ws, size_t ws_size,
                              hipStream_t stream) {
    const float* x      = (const float*)d_in[0];
    const int*   eidx   = (const int*)d_in[1];
    const float* W0     = (const float*)d_in[2];
    const float* a_src0 = (const float*)d_in[3];
    const float* a_dst0 = (const float*)d_in[4];
    const float* g0     = (const float*)d_in[6];
    const float* be0    = (const float*)d_in[7];
    const float* W1     = (const float*)d_in[8];
    const float* a_src1 = (const float*)d_in[9];
    const float* a_dst1 = (const float*)d_in[10];
    const float* g1     = (const float*)d_in[12];
    const float* be1    = (const float*)d_in[13];
    const float* Wc     = (const float*)d_in[14];
    const float* bc     = (const float*)d_in[15];
    float* out = (float*)d_out;

    const int E = in_sizes[1] / 2;
    const int* esrc = eidx;
    const int* edst = eidx + E;

    char* ws = (char*)d_ws;
    size_t off = 0;
    auto alloc = [&](size_t bytes) {
        void* p = ws + off;
        off += (bytes + 255) & ~(size_t)255;
        return p;
    };
    float* out1    = (float*)alloc((size_t)NN * 256 * 4);
    short* h0b     = (short*)alloc((size_t)NN * 256 * 2);
    short* xb      = (short*)alloc((size_t)NN * 256 * 2);
    float* s0      = (float*)alloc((size_t)NN * 16 * 4);
    float* s1      = (float*)alloc((size_t)NN * 16 * 4);
    float* v1      = (float*)alloc(4096 * 4);
    float* h_gat0  = (float*)alloc((size_t)NN * 256 * 4);
    float* hact    = (float*)alloc((size_t)NN * 256 * 4);
    short* hactb   = (short*)alloc((size_t)NN * 256 * 2);
    short* agg1bf  = (short*)alloc((size_t)NN * 2048 * 2);
    short* W0T     = (short*)alloc((size_t)256 * 256 * 2);
    short* W1pT    = (short*)alloc((size_t)256 * 2048 * 2);
    short* WcT     = (short*)alloc((size_t)64 * 256 * 2);
    short* hfinbf  = (short*)alloc((size_t)NN * 256 * 2);
    float* stats   = (float*)alloc(1024 * 4);
    int* counts    = (int*)alloc(NN * 4);
    int* offsets   = (int*)alloc((NN + 16) * 4);
    int* cursor    = (int*)alloc(NN * 4);
    int* elist     = (int*)alloc((size_t)(E + NN) * 4);
    float* pbuf    = (float*)alloc((size_t)(E + NN) * 8 * 4);
    float* dinv    = (float*)alloc((size_t)NN * 8 * 4);

    float* stats0 = stats;
    float* stats1 = stats + 512;

    hipMemsetAsync(stats, 0, 1024 * 4, stream);

    // CSR build
    init_counts_kernel<<<(NN + 255) / 256, 256, 0, stream>>>(counts, NN);
    count_edges_kernel<<<(E + 255) / 256, 256, 0, stream>>>(edst, counts, E);
    scan_kernel<<<1, 1024, 0, stream>>>(counts, offsets, cursor, elist, NN);
    scatter_edges_kernel<<<(E + 255) / 256, 256, 0, stream>>>(esrc, edst, cursor, elist, E);

    // precomputes
    cast_bf16_kernel<<<(NN * 64 + 255) / 256, 256, 0, stream>>>(
        (const floatx4*)x, (short4*)xb, NN * 64);
    prep_w0t_kernel<<<256, 256, 0, stream>>>(W0, W0T);
    prep_v1_kernel<<<16, 256, 0, stream>>>(W1, a_src1, a_dst1, v1);
    transpose_w1_kernel<<<dim3(8, 8, 8), 256, 0, stream>>>(W1, W1pT);
    prep_wct_kernel<<<NCLS, 256, 0, stream>>>(Wc, WcT);

    // layer 0
    {
        dim3 grid(4, (NN + 63) / 64);
        gemm_bf16_v2<<<grid, 256, 0, stream>>>(xb, W0T, nullptr, h0b, nullptr, NN, 256, 256, 1.0f);
    }
    score0_kernel<<<NN, 256, 0, stream>>>((const unsigned short*)h0b, a_src0, a_dst0, s0);
    pden_wave<<<(NN + 3) / 4, 256, 0, stream>>>(s0, offsets, counts, elist, pbuf, dinv);
    agg0_wave<<<(NN + 3) / 4, 256, 0, stream>>>(
        (const unsigned short*)h0b, pbuf, dinv, offsets, counts, elist, h_gat0);
    bn_stats_kernel<<<256, 256, 0, stream>>>(h_gat0, stats0, NN);
    bn_apply_kernel<<<(NN * 256 + 255) / 256, 256, 0, stream>>>(
        h_gat0, stats0, g0, be0, nullptr, hact, hactb, NN * 256);

    // layer 1
    score1_kernel<<<NN, 256, 0, stream>>>((const unsigned short*)hactb, v1, s1);
    pden_wave<<<(NN + 3) / 4, 256, 0, stream>>>(s1, offsets, counts, elist, pbuf, dinv);
    agg1_wave<<<(NN + 3) / 4, 256, 0, stream>>>(
        (const unsigned short*)hactb, pbuf, dinv, offsets, counts, elist, agg1bf);
    {
        dim3 grid(4, (NN + 63) / 64);
        gemm_bf16_v2<<<grid, 256, 0, stream>>>(agg1bf, W1pT, out1, nullptr, nullptr, NN, 256, 2048, 0.125f);
    }
    bn_stats_kernel<<<256, 256, 0, stream>>>(out1, stats1, NN);
    bn_apply_kernel<<<(NN * 256 + 255) / 256, 256, 0, stream>>>(
        out1, stats1, g1, be1, hact, nullptr, hfinbf, NN * 256);

    // classifier
    {
        dim3 grid(1, (NN + 63) / 64);
        gemm_bf16_v2<<<grid, 256, 0, stream>>>(hfinbf, WcT, out, nullptr, bc, NN, NCLS, 256, 1.0f);
    }
}

// Round 6
// 273.232 us; speedup vs baseline: 2.3405x; 1.1535x over previous
//
#include <hip/hip_runtime.h>
#include <math.h>

#define NN 10000
#define HEADS 8
#define NCLS 40
#define CHK 64
#define LOG2E 1.4426950408889634f

typedef __attribute__((ext_vector_type(8))) short short8;
typedef __attribute__((ext_vector_type(4))) float floatx4;

static __device__ __forceinline__ short f2bf(float f) {
    unsigned u = __builtin_bit_cast(unsigned, f);
    unsigned r = (u + 0x7fff + ((u >> 16) & 1)) >> 16;
    return (short)r;
}
static __device__ __forceinline__ float bf2f(unsigned short u) {
    unsigned x = ((unsigned)u) << 16;
    return __builtin_bit_cast(float, x);
}
static __device__ __forceinline__ void gl2lds16(const void* g, void* l) {
    __builtin_amdgcn_global_load_lds(
        (const __attribute__((address_space(1))) unsigned int*)g,
        (__attribute__((address_space(3))) unsigned int*)l, 16, 0, 0);
}

// ---------------- bf16 MFMA GEMM v3: BK=64, XOR-swizzled LDS, optional stats epilogue ----
// C[M,N] = alpha*A[M,K]@Bt[N,K]^T + bias. 256 thr = 4 waves; wave w owns cols [w*16,w*16+16).
// LDS chunk (row, c) stored at slot (c ^ (row&7)) -> fragment b128 reads are 2-way (free).
__global__ __launch_bounds__(256) void gemm_bf16_v3(
    const short* __restrict__ A, const short* __restrict__ Bt,
    float* __restrict__ C, short* __restrict__ Cbf, const float* __restrict__ bias,
    float* __restrict__ stats, int M, int Nn, int K, float alpha)
{
    __shared__ short As[64 * 64];
    __shared__ short Bs[64 * 64];
    const int tid = threadIdx.x;
    const int w = tid >> 6, L = tid & 63;
    const int quad = L >> 4, lr = L & 15;
    const int col0 = blockIdx.x * 64, row0 = blockIdx.y * 64;

    // staging: lane L, call c in {0,1}: row = w*16 + c*8 + (L>>3), swizzled chunk = (L&7)^(L>>3)
    const int srow = w * 16 + (L >> 3);
    const int schunk = (L & 7) ^ (L >> 3);       // (row&7) == (L>>3) for both calls
    int ga0 = row0 + srow;     if (ga0 > M - 1)  ga0 = M - 1;
    int ga1 = row0 + srow + 8; if (ga1 > M - 1)  ga1 = M - 1;
    int gb0 = col0 + srow;     if (gb0 > Nn - 1) gb0 = Nn - 1;
    int gb1 = col0 + srow + 8; if (gb1 > Nn - 1) gb1 = Nn - 1;
    const short* agp0 = A + (size_t)ga0 * K + schunk * 8;
    const short* agp1 = A + (size_t)ga1 * K + schunk * 8;
    const short* bgp0 = Bt + (size_t)gb0 * K + schunk * 8;
    const short* bgp1 = Bt + (size_t)gb1 * K + schunk * 8;
    short* alp0 = &As[w * 1024];
    short* alp1 = &As[w * 1024 + 512];
    short* blp0 = &Bs[w * 1024];
    short* blp1 = &Bs[w * 1024 + 512];

    floatx4 acc[4];
    const floatx4 zf = {0.f, 0.f, 0.f, 0.f};
    #pragma unroll
    for (int i = 0; i < 4; i++) acc[i] = zf;

    for (int k0 = 0; k0 < K; k0 += 64) {
        gl2lds16(agp0 + k0, alp0);
        gl2lds16(agp1 + k0, alp1);
        gl2lds16(bgp0 + k0, blp0);
        gl2lds16(bgp1 + k0, blp1);
        __syncthreads();
        #pragma unroll
        for (int ks = 0; ks < 2; ks++) {
            const int sl = ((ks * 4 + quad) ^ (lr & 7)) * 8;
            short8 bfr = *(const short8*)&Bs[(w * 16 + lr) * 64 + sl];
            #pragma unroll
            for (int i = 0; i < 4; i++) {
                short8 afr = *(const short8*)&As[(i * 16 + lr) * 64 + sl];
                acc[i] = __builtin_amdgcn_mfma_f32_16x16x32_bf16(afr, bfr, acc[i], 0, 0, 0);
            }
        }
        __syncthreads();
    }
    const int ccol = col0 + w * 16 + lr;
    float s = 0.f, s2 = 0.f;
    if (ccol < Nn) {
        float bv = bias ? bias[ccol] : 0.f;
        #pragma unroll
        for (int i = 0; i < 4; i++) {
            #pragma unroll
            for (int r = 0; r < 4; r++) {
                int crow = row0 + i * 16 + quad * 4 + r;
                if (crow < M) {
                    float v = alpha * acc[i][r] + bv;
                    if (C)   C[(size_t)crow * Nn + ccol] = v;
                    if (Cbf) Cbf[(size_t)crow * Nn + ccol] = f2bf(v);
                    s += v; s2 += v * v;
                }
            }
        }
    }
    if (stats) {   // fused BN-stats: reduce 4 quads (same ccol), one atomic pair per col
        s  += __shfl_xor(s, 16, 64);  s  += __shfl_xor(s, 32, 64);
        s2 += __shfl_xor(s2, 16, 64); s2 += __shfl_xor(s2, 32, 64);
        if (L < 16 && ccol < Nn) {
            atomicAdd(&stats[ccol], s);
            atomicAdd(&stats[256 + ccol], s2);
        }
    }
}

// ---------------- CSR build ----------------
__global__ void count_edges_kernel(const int* __restrict__ dst, int* counts, int E) {
    int e = blockIdx.x * 256 + threadIdx.x;
    if (e < E) atomicAdd(&counts[dst[e]], 1);
}

// single-block scan; adds the self-loop (+1) and writes final degree back to counts
__global__ __launch_bounds__(1024) void scan_kernel(
    int* counts, int* offsets, int* cursor, int* elist, int n)
{
    const int P = (n + 1023) >> 10;
    __shared__ int wsum[16];
    int tid = threadIdx.x, lane = tid & 63, wid = tid >> 6;
    int base = tid * P;
    int local[16];
    int deg[16];
    int s = 0;
    for (int j = 0; j < P; j++) {
        int i = base + j;
        local[j] = s;
        deg[j] = (i < n) ? counts[i] + 1 : 0;   // +1 self-loop
        s += deg[j];
    }
    int inc = s;
    #pragma unroll
    for (int off = 1; off < 64; off <<= 1) {
        int tv = __shfl_up(inc, off, 64);
        if (lane >= off) inc += tv;
    }
    if (lane == 63) wsum[wid] = inc;
    __syncthreads();
    if (tid < 16) {
        int v = wsum[tid];
        int winc = v;
        #pragma unroll
        for (int off = 1; off < 16; off <<= 1) {
            int tv = __shfl_up(winc, off, 16);
            if (tid >= off) winc += tv;
        }
        wsum[tid] = winc - v;
    }
    __syncthreads();
    int excl = inc - s + wsum[wid];
    for (int j = 0; j < P; j++) {
        int i = base + j;
        if (i < n) {
            int o = excl + local[j];
            counts[i] = deg[j];
            offsets[i] = o;
            elist[o] = i;       // self-loop in slot 0
            cursor[i] = o + 1;
        }
    }
}

__global__ void scatter_edges_kernel(const int* __restrict__ src, const int* __restrict__ dst,
                                     int* cursor, int* elist, int E) {
    int e = blockIdx.x * 256 + threadIdx.x;
    if (e < E) {
        int d = dst[e];
        int pos = atomicAdd(&cursor[d], 1);
        elist[pos] = src[e];
    }
}

// ---------------- all weight/input prep in one launch ----------------
__global__ __launch_bounds__(256) void prep_all(
    const float* __restrict__ x, const float* __restrict__ W0,
    const float* __restrict__ W1, const float* __restrict__ a_src1,
    const float* __restrict__ a_dst1, const float* __restrict__ Wc,
    short* __restrict__ xb, short* __restrict__ W0T, float* __restrict__ v1,
    short* __restrict__ W1pT, short* __restrict__ WcT)
{
    __shared__ float tile[32][33];
    const int b = blockIdx.x, t = threadIdx.x;
    if (b < 2500) {                 // cast x -> bf16 (x4 vectorized)
        int i = b * 256 + t;
        floatx4 v = ((const floatx4*)x)[i];
        short4 o = {f2bf(v[0]), f2bf(v[1]), f2bf(v[2]), f2bf(v[3])};
        ((short4*)xb)[i] = o;
    } else if (b < 2756) {          // W0T [256][256]
        int o = b - 2500;
        W0T[o * 256 + t] = f2bf(W0[t * 256 + o]);
    } else if (b < 2772) {          // v1 = folded W1·a  [256 f][16 j]
        int idx = (b - 2756) * 256 + t;
        int f = idx >> 4, j = idx & 15;
        int h = j & 7;
        const float* a = (j < 8) ? a_src1 : a_dst1;
        float s = 0.f;
        for (int c = 0; c < 256; c++)
            s += W1[f * 2048 + h * 256 + c] * a[h * 256 + c];
        v1[idx] = s;
    } else if (b < 3284) {          // W1pT bf16 [256 c][2048 hf]
        int id = b - 2772;
        int h = id >> 6, f0 = ((id >> 3) & 7) * 32, c0 = (id & 7) * 32;
        int tx = t & 31, ty = t >> 5;
        for (int r = ty; r < 32; r += 8)
            tile[r][tx] = W1[(size_t)(f0 + r) * 2048 + h * 256 + c0 + tx];
        __syncthreads();
        for (int r = ty; r < 32; r += 8)
            W1pT[(size_t)(c0 + r) * 2048 + h * 256 + f0 + tx] = f2bf(tile[tx][r]);
    } else {                        // WcT bf16 [40][256]
        int o = b - 3284;
        WcT[o * 256 + t] = f2bf(Wc[t * 40 + o]);
    }
}

// ---------------- layer-0 node scores: wave per node ----------------
__global__ __launch_bounds__(256) void score0_wave(
    const unsigned short* __restrict__ h0b, const float* __restrict__ a_src,
    const float* __restrict__ a_dst, float* __restrict__ s0)
{
    const int wid = threadIdx.x >> 6, L = threadIdx.x & 63;
    const int n = blockIdx.x * 4 + wid;
    if (n >= NN) return;
    ushort4 vv = *(const ushort4*)(h0b + (size_t)n * 256 + 4 * L);
    floatx4 as = *(const floatx4*)(a_src + 4 * L);
    floatx4 ad = *(const floatx4*)(a_dst + 4 * L);
    float v0 = bf2f(vv.x), v1_ = bf2f(vv.y), v2 = bf2f(vv.z), v3 = bf2f(vv.w);
    float ps = v0 * as[0] + v1_ * as[1] + v2 * as[2] + v3 * as[3];
    float pd = v0 * ad[0] + v1_ * ad[1] + v2 * ad[2] + v3 * ad[3];
    #pragma unroll
    for (int off = 1; off < 8; off <<= 1) {
        ps += __shfl_xor(ps, off, 64);
        pd += __shfl_xor(pd, off, 64);
    }
    if ((L & 7) == 0) {
        s0[n * 16 + (L >> 3)] = ps;
        s0[n * 16 + 8 + (L >> 3)] = pd;
    }
}

// ---------------- fused softmax(no-max)+aggregate, layer 0 ----------------
__global__ __launch_bounds__(256) void agg0_fused(
    const unsigned short* __restrict__ h0b, const float* __restrict__ s0,
    const int* __restrict__ offsets, const int* __restrict__ counts,
    const int* __restrict__ elist, float* __restrict__ out)
{
    __shared__ float pw_s[4][CHK * 8];
    __shared__ int   sn_s[4][CHK];
    const int wid = threadIdx.x >> 6, L = threadIdx.x & 63;
    const int n = blockIdx.x * 4 + wid;
    if (n >= NN) return;
    float* pw = pw_s[wid];
    int*   sw = sn_s[wid];
    const int deg = counts[n], start = offsets[n];
    const int hL = L >> 3;

    floatx4 sda = *(const floatx4*)(s0 + n * 16 + 8);
    floatx4 sdb = *(const floatx4*)(s0 + n * 16 + 12);
    float sd[8] = {sda[0], sda[1], sda[2], sda[3], sdb[0], sdb[1], sdb[2], sdb[3]};
    float lp[8] = {0.f, 0.f, 0.f, 0.f, 0.f, 0.f, 0.f, 0.f};
    float a0 = 0.f, a1 = 0.f, a2 = 0.f, a3 = 0.f;

    for (int e0 = 0; e0 < deg; e0 += CHK) {
        int ch = deg - e0; if (ch > CHK) ch = CHK;
        if (L < ch) {
            int sn = elist[start + e0 + L];
            sw[L] = sn;
            floatx4 ssa = *(const floatx4*)(s0 + sn * 16);
            floatx4 ssb = *(const floatx4*)(s0 + sn * 16 + 4);
            float ss[8] = {ssa[0], ssa[1], ssa[2], ssa[3], ssb[0], ssb[1], ssb[2], ssb[3]};
            float p[8];
            #pragma unroll
            for (int h = 0; h < 8; h++) {
                float v = ss[h] + sd[h];
                v = (v > 0.f) ? v : 0.2f * v;
                p[h] = exp2f(v * LOG2E);
                lp[h] += p[h];
            }
            floatx4 p0 = {p[0], p[1], p[2], p[3]};
            floatx4 p1 = {p[4], p[5], p[6], p[7]};
            *(floatx4*)&pw[L * 8] = p0;
            *(floatx4*)&pw[L * 8 + 4] = p1;
        }
        for (int e = 0; e < ch; e++) {
            float wgt = pw[e * 8 + hL];
            ushort4 vv = *(const ushort4*)(h0b + (size_t)sw[e] * 256 + 4 * L);
            a0 += wgt * bf2f(vv.x);
            a1 += wgt * bf2f(vv.y);
            a2 += wgt * bf2f(vv.z);
            a3 += wgt * bf2f(vv.w);
        }
    }
    #pragma unroll
    for (int off = 1; off < 64; off <<= 1)
        #pragma unroll
        for (int h = 0; h < 8; h++)
            lp[h] += __shfl_xor(lp[h], off, 64);
    float inv = 1.f / lp[hL];
    floatx4 o = {a0 * inv, a1 * inv, a2 * inv, a3 * inv};
    *(floatx4*)(out + (size_t)n * 256 + 4 * L) = o;
}

// ---------------- fused softmax(no-max)+aggregate, layer 1 (8 heads) ----------------
__global__ __launch_bounds__(256) void agg1_fused(
    const unsigned short* __restrict__ hb, const float* __restrict__ s1,
    const int* __restrict__ offsets, const int* __restrict__ counts,
    const int* __restrict__ elist, short* __restrict__ aggout)
{
    __shared__ float pw_s[4][CHK * 8];
    __shared__ int   sn_s[4][CHK];
    const int wid = threadIdx.x >> 6, L = threadIdx.x & 63;
    const int n = blockIdx.x * 4 + wid;
    if (n >= NN) return;
    float* pw = pw_s[wid];
    int*   sw = sn_s[wid];
    const int deg = counts[n], start = offsets[n];

    floatx4 sda = *(const floatx4*)(s1 + n * 16 + 8);
    floatx4 sdb = *(const floatx4*)(s1 + n * 16 + 12);
    float sd[8] = {sda[0], sda[1], sda[2], sda[3], sdb[0], sdb[1], sdb[2], sdb[3]};
    float lp[8] = {0.f, 0.f, 0.f, 0.f, 0.f, 0.f, 0.f, 0.f};
    float acc[8][4];
    #pragma unroll
    for (int h = 0; h < 8; h++)
        #pragma unroll
        for (int f = 0; f < 4; f++) acc[h][f] = 0.f;

    for (int e0 = 0; e0 < deg; e0 += CHK) {
        int ch = deg - e0; if (ch > CHK) ch = CHK;
        if (L < ch) {
            int sn = elist[start + e0 + L];
            sw[L] = sn;
            floatx4 ssa = *(const floatx4*)(s1 + sn * 16);
            floatx4 ssb = *(const floatx4*)(s1 + sn * 16 + 4);
            float ss[8] = {ssa[0], ssa[1], ssa[2], ssa[3], ssb[0], ssb[1], ssb[2], ssb[3]};
            float p[8];
            #pragma unroll
            for (int h = 0; h < 8; h++) {
                float v = ss[h] + sd[h];
                v = (v > 0.f) ? v : 0.2f * v;
                p[h] = exp2f(v * LOG2E);
                lp[h] += p[h];
            }
            floatx4 p0 = {p[0], p[1], p[2], p[3]};
            floatx4 p1 = {p[4], p[5], p[6], p[7]};
            *(floatx4*)&pw[L * 8] = p0;
            *(floatx4*)&pw[L * 8 + 4] = p1;
        }
        for (int e = 0; e < ch; e++) {
            floatx4 pv0 = *(const floatx4*)&pw[e * 8];
            floatx4 pv1 = *(const floatx4*)&pw[e * 8 + 4];
            ushort4 vv = *(const ushort4*)(hb + (size_t)sw[e] * 256 + 4 * L);
            float v0 = bf2f(vv.x), v1_ = bf2f(vv.y), v2 = bf2f(vv.z), v3 = bf2f(vv.w);
            #pragma unroll
            for (int h = 0; h < 4; h++) {
                acc[h][0] += pv0[h] * v0;
                acc[h][1] += pv0[h] * v1_;
                acc[h][2] += pv0[h] * v2;
                acc[h][3] += pv0[h] * v3;
                acc[h + 4][0] += pv1[h] * v0;
                acc[h + 4][1] += pv1[h] * v1_;
                acc[h + 4][2] += pv1[h] * v2;
                acc[h + 4][3] += pv1[h] * v3;
            }
        }
    }
    #pragma unroll
    for (int off = 1; off < 64; off <<= 1)
        #pragma unroll
        for (int h = 0; h < 8; h++)
            lp[h] += __shfl_xor(lp[h], off, 64);
    #pragma unroll
    for (int h = 0; h < 8; h++) {
        float inv = 1.f / lp[h];
        short4 o = {f2bf(acc[h][0] * inv), f2bf(acc[h][1] * inv),
                    f2bf(acc[h][2] * inv), f2bf(acc[h][3] * inv)};
        *(short4*)(aggout + (size_t)n * 2048 + h * 256 + 4 * L) = o;
    }
}

// ---------------- batchnorm ----------------
__global__ __launch_bounds__(256) void bn_stats_kernel(const float* __restrict__ x, float* stats, int n) {
    int t = threadIdx.x;
    float s = 0.f, s2 = 0.f;
    for (int r = blockIdx.x; r < n; r += gridDim.x) {
        float v = x[(size_t)r * 256 + t];
        s += v; s2 += v * v;
    }
    atomicAdd(&stats[t], s);
    atomicAdd(&stats[256 + t], s2);
}

// BN + ELU + (write hact fp32 & bf16) + layer-1 score, one block per node
__global__ __launch_bounds__(256) void bnapply_score1(
    const float* __restrict__ xg, const float* __restrict__ stats,
    const float* __restrict__ g, const float* __restrict__ be,
    const float* __restrict__ v1, float* __restrict__ hact,
    short* __restrict__ hactb, float* __restrict__ s1)
{
    __shared__ float row[256];
    __shared__ float part[16][17];
    const int n = blockIdx.x, t = threadIdx.x;
    const float invN = 1.0f / NN;
    float mu = stats[t] * invN;
    float var = stats[256 + t] * invN - mu * mu;
    float v = g[t] * (xg[(size_t)n * 256 + t] - mu) * rsqrtf(var + 1e-5f) + be[t];
    v = (v > 0.f) ? v : (expf(v) - 1.f);   // ELU
    hact[(size_t)n * 256 + t] = v;
    hactb[(size_t)n * 256 + t] = f2bf(v);
    row[t] = v;
    __syncthreads();
    int j = t & 15, f0 = t >> 4;
    float p = 0.f;
    #pragma unroll
    for (int k = 0; k < 16; k++)
        p += row[f0 * 16 + k] * v1[(f0 * 16 + k) * 16 + j];
    part[f0][j] = p;
    __syncthreads();
    if (t < 16) {
        float s = 0.f;
        #pragma unroll
        for (int k = 0; k < 16; k++) s += part[k][t];
        s1[n * 16 + t] = s;
    }
}

__global__ __launch_bounds__(256) void bn_apply_kernel(
    const float* __restrict__ x, const float* __restrict__ stats,
    const float* __restrict__ g, const float* __restrict__ be,
    const float* __restrict__ resid, short* __restrict__ ybf, int total)
{
    int i = blockIdx.x * 256 + threadIdx.x;
    if (i >= total) return;
    int c = i & 255;
    const float invN = 1.0f / NN;
    float mu = stats[c] * invN;
    float var = stats[256 + c] * invN - mu * mu;
    float v = g[c] * (x[i] - mu) * rsqrtf(var + 1e-5f) + be[c];
    v = (v > 0.f) ? v : (expf(v) - 1.f);   // ELU
    v += resid[i];
    ybf[i] = f2bf(v);
}

// ---------------- launch ----------------
extern "C" void kernel_launch(void* const* d_in, const int* in_sizes, int n_in,
                              void* d_out, int out_size, void* d_ws, size_t ws_size,
                              hipStream_t stream) {
    const float* x      = (const float*)d_in[0];
    const int*   eidx   = (const int*)d_in[1];
    const float* W0     = (const float*)d_in[2];
    const float* a_src0 = (const float*)d_in[3];
    const float* a_dst0 = (const float*)d_in[4];
    const float* g0     = (const float*)d_in[6];
    const float* be0    = (const float*)d_in[7];
    const float* W1     = (const float*)d_in[8];
    const float* a_src1 = (const float*)d_in[9];
    const float* a_dst1 = (const float*)d_in[10];
    const float* g1     = (const float*)d_in[12];
    const float* be1    = (const float*)d_in[13];
    const float* Wc     = (const float*)d_in[14];
    const float* bc     = (const float*)d_in[15];
    float* out = (float*)d_out;

    const int E = in_sizes[1] / 2;
    const int* esrc = eidx;
    const int* edst = eidx + E;

    char* ws = (char*)d_ws;
    size_t off = 0;
    auto alloc = [&](size_t bytes) {
        void* p = ws + off;
        off += (bytes + 255) & ~(size_t)255;
        return p;
    };
    // stats + counts contiguous -> single memset
    float* stats   = (float*)alloc(1024 * 4);               // 4096 B (aligned)
    int*   counts  = (int*)alloc(NN * 4);
    float* out1    = (float*)alloc((size_t)NN * 256 * 4);
    short* h0b     = (short*)alloc((size_t)NN * 256 * 2);
    short* xb      = (short*)alloc((size_t)NN * 256 * 2);
    float* s0      = (float*)alloc((size_t)NN * 16 * 4);
    float* s1      = (float*)alloc((size_t)NN * 16 * 4);
    float* v1      = (float*)alloc(4096 * 4);
    float* h_gat0  = (float*)alloc((size_t)NN * 256 * 4);
    float* hact    = (float*)alloc((size_t)NN * 256 * 4);
    short* hactb   = (short*)alloc((size_t)NN * 256 * 2);
    short* agg1bf  = (short*)alloc((size_t)NN * 2048 * 2);
    short* W0T     = (short*)alloc((size_t)256 * 256 * 2);
    short* W1pT    = (short*)alloc((size_t)256 * 2048 * 2);
    short* WcT     = (short*)alloc((size_t)64 * 256 * 2);
    short* hfinbf  = (short*)alloc((size_t)NN * 256 * 2);
    int* offsets   = (int*)alloc((NN + 16) * 4);
    int* cursor    = (int*)alloc(NN * 4);
    int* elist     = (int*)alloc((size_t)(E + NN) * 4);

    float* stats0 = stats;
    float* stats1 = stats + 512;

    hipMemsetAsync(stats, 0, 1024 * 4 + NN * 4, stream);   // stats0+stats1+counts

    // CSR build (3 kernels)
    count_edges_kernel<<<(E + 255) / 256, 256, 0, stream>>>(edst, counts, E);
    scan_kernel<<<1, 1024, 0, stream>>>(counts, offsets, cursor, elist, NN);
    scatter_edges_kernel<<<(E + 255) / 256, 256, 0, stream>>>(esrc, edst, cursor, elist, E);

    // all prep in one launch
    prep_all<<<3324, 256, 0, stream>>>(x, W0, W1, a_src1, a_dst1, Wc,
                                       xb, W0T, v1, W1pT, WcT);

    // layer 0
    {
        dim3 grid(4, (NN + 63) / 64);
        gemm_bf16_v3<<<grid, 256, 0, stream>>>(xb, W0T, nullptr, h0b, nullptr, nullptr,
                                               NN, 256, 256, 1.0f);
    }
    score0_wave<<<(NN + 3) / 4, 256, 0, stream>>>(
        (const unsigned short*)h0b, a_src0, a_dst0, s0);
    agg0_fused<<<(NN + 3) / 4, 256, 0, stream>>>(
        (const unsigned short*)h0b, s0, offsets, counts, elist, h_gat0);
    bn_stats_kernel<<<256, 256, 0, stream>>>(h_gat0, stats0, NN);
    bnapply_score1<<<NN, 256, 0, stream>>>(h_gat0, stats0, g0, be0, v1, hact, hactb, s1);

    // layer 1
    agg1_fused<<<(NN + 3) / 4, 256, 0, stream>>>(
        (const unsigned short*)hactb, s1, offsets, counts, elist, agg1bf);
    {
        dim3 grid(4, (NN + 63) / 64);
        gemm_bf16_v3<<<grid, 256, 0, stream>>>(agg1bf, W1pT, out1, nullptr, nullptr, stats1,
                                               NN, 256, 2048, 0.125f);
    }
    bn_apply_kernel<<<(NN * 256 + 255) / 256, 256, 0, stream>>>(
        out1, stats1, g1, be1, hact, hfinbf, NN * 256);

    // classifier
    {
        dim3 grid(1, (NN + 63) / 64);
        gemm_bf16_v3<<<grid, 256, 0, stream>>>(hfinbf, WcT, out, nullptr, bc, nullptr,
                                               NN, NCLS, 256, 1.0f);
    }
}